// Round 1
// baseline (16514.955 us; speedup 1.0000x reference)
//
#include <hip/hip_runtime.h>

// ---------------------------------------------------------------------------
// DeformableAttnBlock — full fp32 implementation (round 0: correctness + sane tiling)
// B=2, T=5, C=192, H=W=64, NH=4, NL=5, NP=4, DH=48
// ---------------------------------------------------------------------------

#define HWPX 4096
#define WX   64
#define TT   5
#define CCH  192
#define TC   960
#define CIQK 976
#define LQ   20480
#define NHH  4
#define NLL  5
#define NPP  4
#define DHH  48
#define BB   2

// bilinear sample with border clamp (grid_sample_border semantics)
__device__ __forceinline__ float bsample(const float* __restrict__ p, float sx, float sy) {
    sx = fminf(fmaxf(sx, 0.f), 63.f);
    sy = fminf(fmaxf(sy, 0.f), 63.f);
    float x0 = floorf(sx), y0 = floorf(sy);
    int ix0 = (int)x0, iy0 = (int)y0;
    int ix1 = ix0 < 63 ? ix0 + 1 : 63;
    int iy1 = iy0 < 63 ? iy0 + 1 : 63;
    float wx = sx - x0, wy = sy - y0;
    float v00 = p[iy0*WX+ix0], v01 = p[iy0*WX+ix1];
    float v10 = p[iy1*WX+ix0], v11 = p[iy1*WX+ix1];
    return (v00*(1.f-wx) + v01*wx)*(1.f-wy) + (v10*(1.f-wx) + v11*wx)*wy;
}

// K1: flow composition. flows layout (B, 5, 2, HW): l0=ff02, l1=ff12, l2=0, l3=fb32, l4=fb42
__global__ __launch_bounds__(256) void k_flow(const float* __restrict__ ff,
                                              const float* __restrict__ fb,
                                              float* __restrict__ flows) {
    int i = blockIdx.x*256 + threadIdx.x;           // b*HW + pix, 8192 total
    int b = i >> 12, pix = i & 4095;
    int x = pix & 63, y = pix >> 6;
    const float* ff01 = ff + (size_t)(b*4+0)*2*HWPX;
    const float* ff12 = ff + (size_t)(b*4+1)*2*HWPX;
    const float* fb32 = fb + (size_t)(b*4+2)*2*HWPX;
    const float* fb43 = fb + (size_t)(b*4+3)*2*HWPX;
    float* F = flows + (size_t)b*NLL*2*HWPX;
    float ax = ff01[pix], ay = ff01[HWPX+pix];
    float sx = bsample(ff12,      (float)x+ax, (float)y+ay);
    float sy = bsample(ff12+HWPX, (float)x+ax, (float)y+ay);
    F[0*2*HWPX + pix]        = ax + sx;
    F[0*2*HWPX + HWPX + pix] = ay + sy;
    F[1*2*HWPX + pix]        = ff12[pix];
    F[1*2*HWPX + HWPX + pix] = ff12[HWPX+pix];
    F[2*2*HWPX + pix]        = 0.f;
    F[2*2*HWPX + HWPX + pix] = 0.f;
    F[3*2*HWPX + pix]        = fb32[pix];
    F[3*2*HWPX + HWPX + pix] = fb32[HWPX+pix];
    float bx = fb43[pix], by = fb43[HWPX+pix];
    float tx = bsample(fb32,      (float)x+bx, (float)y+by);
    float ty = bsample(fb32+HWPX, (float)x+bx, (float)y+by);
    F[4*2*HWPX + pix]        = bx + tx;
    F[4*2*HWPX + HWPX + pix] = by + ty;
}

// K2: assemble qk_in (B, 976, HW): [warp02, warp12, frame2, warp32, warp42, ff(8), fb(8)]
__global__ __launch_bounds__(256) void k_qkin(const float* __restrict__ frame,
                                              const float* __restrict__ ff,
                                              const float* __restrict__ fb,
                                              const float* __restrict__ flows,
                                              float* __restrict__ qk) {
    int pix = blockIdx.x*256 + threadIdx.x;
    int c = blockIdx.y, b = blockIdx.z;
    float* dst = qk + ((size_t)b*CIQK + c)*HWPX + pix;
    if (c >= TC) {
        int k = c - TC;
        const float* src = (k < 8) ? ff + (size_t)(b*8+k)*HWPX : fb + (size_t)(b*8+k-8)*HWPX;
        *dst = src[pix];
        return;
    }
    int slot = c / CCH, cc = c % CCH;
    const float* plane = frame + ((size_t)(b*TT+slot)*CCH + cc)*HWPX;
    if (slot == 2) { *dst = plane[pix]; return; }
    const float* F = flows + ((size_t)(b*NLL+slot)*2)*HWPX;
    float fx = F[pix], fy = F[HWPX+pix];
    int x = pix & 63, y = pix >> 6;
    *dst = bsample(plane, (float)x+fx, (float)y+fy);
}

// K3: generic 3x3 conv, NCHW, pad=DIL, dilation=DIL. Tile: 64 co x (2 rows x 64 px).
// Thread: 8 co x 4 px. Optional channel-split second input (ffn1 concat), leaky, residual.
template<int CI_T, int DIL, bool LEAKY, bool HASRES>
__global__ __launch_bounds__(256) void k_conv3(
    const float* __restrict__ in1, long in1_str,
    const float* __restrict__ in2, long in2_str, int ci_split,
    const float* __restrict__ wgt, const float* __restrict__ bias,
    const float* __restrict__ res,
    float* __restrict__ out, int CO)
{
    constexpr int R  = 2 + 2*DIL;   // staged rows
    constexpr int XW = 68;          // padded stage width
    __shared__ float s_in[8][R][XW];
    __shared__ float s_w[64][8][9];
    int tid = threadIdx.x;
    int cotile = blockIdx.x, ytile = blockIdx.y, img = blockIdx.z;
    int ybase = ytile*2;
    int pxg = tid & 31, cog = tid >> 5;     // pxg 0..31, cog 0..7
    int py = pxg >> 4;                       // 0..1
    int x0 = (pxg & 15) * 4;
    float acc[8][4] = {};
    const float* in1i = in1 + (size_t)img*in1_str;
    const float* in2i = in2 ? in2 + (size_t)img*in2_str : nullptr;

    for (int k0 = 0; k0 < CI_T; k0 += 8) {
        // stage input tile: 8 ci x R rows x (64+2*DIL) cols (zero-padded)
        for (int li = tid; li < 8*R*XW; li += 256) {
            int ci = li / (R*XW); int rem = li % (R*XW);
            int r = rem / XW; int lx = rem % XW;
            int xx = lx - DIL; int yy = ybase - DIL + r;
            float v = 0.f;
            if (xx >= 0 && xx < 64 && yy >= 0 && yy < 64) {
                int cg = k0 + ci;
                const float* src = (cg < ci_split) ? in1i + (size_t)cg*HWPX
                                                   : in2i + (size_t)(cg - ci_split)*HWPX;
                v = src[yy*64 + xx];
            }
            s_in[ci][r][lx] = v;
        }
        // stage weights: 64 co x 8 ci x 9
        for (int li = tid; li < 64*8*9; li += 256) {
            int co = li / 72; int rem = li % 72; int ci = rem / 9; int k = rem % 9;
            s_w[co][ci][k] = wgt[((long)(cotile*64+co)*CI_T + k0 + ci)*9 + k];
        }
        __syncthreads();
        #pragma unroll
        for (int ci = 0; ci < 8; ++ci) {
            #pragma unroll
            for (int ky = 0; ky < 3; ++ky) {
                float iv[3][4];
                #pragma unroll
                for (int kx = 0; kx < 3; ++kx)
                    #pragma unroll
                    for (int j = 0; j < 4; ++j)
                        iv[kx][j] = s_in[ci][py + ky*DIL][x0 + j + kx*DIL];
                #pragma unroll
                for (int i = 0; i < 8; ++i) {
                    float w0 = s_w[cog*8+i][ci][ky*3+0];
                    float w1 = s_w[cog*8+i][ci][ky*3+1];
                    float w2 = s_w[cog*8+i][ci][ky*3+2];
                    #pragma unroll
                    for (int j = 0; j < 4; ++j)
                        acc[i][j] += w0*iv[0][j] + w1*iv[1][j] + w2*iv[2][j];
                }
            }
        }
        __syncthreads();
    }
    int yo = ybase + py;
    #pragma unroll
    for (int i = 0; i < 8; ++i) {
        int co = cotile*64 + cog*8 + i;
        float bv = bias[co];
        long obase = ((long)img*CO + co)*HWPX + yo*64 + x0;
        #pragma unroll
        for (int j = 0; j < 4; ++j) {
            float v = acc[i][j] + bv;
            if (LEAKY) v = v >= 0.f ? v : 0.1f*v;
            if (HASRES) v += res[obase + j];
            out[obase + j] = v;
        }
    }
}

// K4/6/9: skinny GEMM (K=192): out[co][px] = sum_ci in[ci][px] * w[co][ci] + b[co]
// per-img. Tile 64 co x 128 px, thread 8 co x 4 px.
// TOK48=1: write (co/48, px, co%48) token-major blocks (for vproj).
template<int TOK48>
__global__ __launch_bounds__(256) void k_gemm(
    const float* __restrict__ in, long in_img_str, int ci_stride, int px_stride,
    const float* __restrict__ w1, const float* __restrict__ bias1,
    const float* __restrict__ w2, const float* __restrict__ bias2,
    int co_split, int CO,
    float* __restrict__ out1, long o1b, long o1t, long o1row,
    float* __restrict__ out2, long o2b, long o2t, long o2row)
{
    __shared__ float s_in[8][128];
    __shared__ float s_w[64][8];
    int tid = threadIdx.x;
    int cotile = blockIdx.x, pxt = blockIdx.y, img = blockIdx.z;
    int px0 = pxt*128;
    int pxg = tid & 31, cog = tid >> 5;
    const float* inb = in + (size_t)img*in_img_str;
    float acc[8][4] = {};

    for (int k0 = 0; k0 < 192; k0 += 8) {
        if (px_stride == 1) {
            int ci = tid >> 5, tok = (tid & 31) * 4;
            float4 v = *(const float4*)(inb + (long)(k0+ci)*ci_stride + px0 + tok);
            ((float4*)s_in[ci])[tok>>2] = v;
        } else {
            int tok = tid >> 1, u = (tid & 1)*4;
            float4 v = *(const float4*)(inb + (long)(px0+tok)*px_stride + k0 + u);
            s_in[u+0][tok] = v.x; s_in[u+1][tok] = v.y;
            s_in[u+2][tok] = v.z; s_in[u+3][tok] = v.w;
        }
        #pragma unroll
        for (int q = 0; q < 2; ++q) {
            int li = tid + q*256;
            int co = li >> 3, ci = li & 7;
            int cg = cotile*64 + co;
            float v = 0.f;
            if (cg < CO) {
                const float* row = (cg < co_split) ? w1 + (long)cg*192
                                                   : w2 + (long)(cg - co_split)*192;
                v = row[k0 + ci];
            }
            s_w[co][ci] = v;
        }
        __syncthreads();
        #pragma unroll
        for (int ci = 0; ci < 8; ++ci) {
            float4 a = ((const float4*)s_in[ci])[pxg];
            #pragma unroll
            for (int i = 0; i < 8; ++i) {
                float wv = s_w[cog*8+i][ci];
                acc[i][0] += wv*a.x; acc[i][1] += wv*a.y;
                acc[i][2] += wv*a.z; acc[i][3] += wv*a.w;
            }
        }
        __syncthreads();
    }
    int b = img / TT, t = img % TT;
    #pragma unroll
    for (int i = 0; i < 8; ++i) {
        int co = cotile*64 + cog*8 + i;
        if (co >= CO) break;
        float bv = (co < co_split) ? bias1[co] : bias2[co - co_split];
        #pragma unroll
        for (int j = 0; j < 4; ++j) {
            float v = acc[i][j] + bv;
            int px = px0 + pxg*4 + j;
            if (TOK48) {
                out1[(long)b*o1b + (long)t*o1t + (long)(co/48)*(48*HWPX) + (long)px*48 + (co%48)] = v;
            } else if (co < co_split) {
                out1[(long)b*o1b + (long)t*o1t + (long)co*o1row + px] = v;
            } else {
                out2[(long)b*o2b + (long)t*o2t + (long)(co - co_split)*o2row + px] = v;
            }
        }
    }
}

// K7: softmax over 20 values at stride LQ (aw: (B, 4*20, LQ))
__global__ __launch_bounds__(256) void k_softmax20(float* __restrict__ aw) {
    int i = blockIdx.x*256 + threadIdx.x;   // B*NH*LQ = 163840
    int lq = i % LQ;
    int bh = i / LQ;
    float* p = aw + (long)bh*20*LQ + lq;
    float e[20];
    float m = -1e30f;
    #pragma unroll
    for (int j = 0; j < 20; ++j) { e[j] = p[j*LQ]; m = fmaxf(m, e[j]); }
    float s = 0.f;
    #pragma unroll
    for (int j = 0; j < 20; ++j) { e[j] = expf(e[j]-m); s += e[j]; }
    float inv = 1.f/s;
    #pragma unroll
    for (int j = 0; j < 20; ++j) p[j*LQ] = e[j]*inv;
}

__device__ __forceinline__ void addtap(float* acc, const float* __restrict__ src, float w) {
    const float4* s4 = (const float4*)src;
    #pragma unroll
    for (int q = 0; q < 12; ++q) {
        float4 v = s4[q];
        acc[q*4+0] += w*v.x; acc[q*4+1] += w*v.y;
        acc[q*4+2] += w*v.z; acc[q*4+3] += w*v.w;
    }
}

// K8: deformable sampling + weighted accumulation.
// vp: (B, 5, 4, HW, 48) token-major value projection; out acc: (B, LQ, 192) token-major.
__global__ __launch_bounds__(256) void k_sample(
    const float* __restrict__ vp, const float* __restrict__ offs,
    const float* __restrict__ aw, const float* __restrict__ flows,
    float* __restrict__ accout)
{
    int blk = blockIdx.x;               // b*320 + sub
    int b = blk / 320, sub = blk % 320;
    int h = threadIdx.x >> 6;
    int lq = sub*64 + (threadIdx.x & 63);
    int pix = lq % HWPX;
    int x = pix & 63, y = pix >> 6;
    const float* offp = offs + ((long)b*160 + h*40)*LQ + lq;
    const float* awp  = aw   + ((long)b*80  + h*20)*LQ + lq;
    float acc[48];
    #pragma unroll
    for (int d = 0; d < 48; ++d) acc[d] = 0.f;

    for (int l = 0; l < NLL; ++l) {
        float fx = flows[((long)(b*NLL+l)*2+0)*HWPX + pix];
        float fy = flows[((long)(b*NLL+l)*2+1)*HWPX + pix];
        const float* vpl = vp + ((long)(b*TT+l)*NHH + h)*HWPX*DHH;
        #pragma unroll
        for (int p = 0; p < NPP; ++p) {
            int o = l*4 + p;
            float ox = offp[(long)(2*o)*LQ];
            float oy = offp[(long)(2*o+1)*LQ];
            float wv = awp[(long)o*LQ];
            float sx = (float)x + ox + fx;       // = loc_x*W - 0.5
            float sy = (float)y + oy + fy;
            float x0f = floorf(sx), y0f = floorf(sy);
            float wx = sx - x0f, wy = sy - y0f;
            int ix0 = (int)x0f, iy0 = (int)y0f;
            float w00 = wv*(1.f-wx)*(1.f-wy), w01 = wv*wx*(1.f-wy);
            float w10 = wv*(1.f-wx)*wy,       w11 = wv*wx*wy;
            bool vx0 = (ix0 >= 0)  && (ix0 <= 63);
            bool vx1 = (ix0 >= -1) && (ix0 <= 62);
            bool vy0 = (iy0 >= 0)  && (iy0 <= 63);
            bool vy1 = (iy0 >= -1) && (iy0 <= 62);
            if (vy0 && vx0) addtap(acc, vpl + (long)(iy0*WX + ix0)*DHH,       w00);
            if (vy0 && vx1) addtap(acc, vpl + (long)(iy0*WX + ix0 + 1)*DHH,   w01);
            if (vy1 && vx0) addtap(acc, vpl + (long)((iy0+1)*WX + ix0)*DHH,   w10);
            if (vy1 && vx1) addtap(acc, vpl + (long)((iy0+1)*WX + ix0+1)*DHH, w11);
        }
    }
    float* dst = accout + ((long)b*LQ + lq)*CCH + h*DHH;
    #pragma unroll
    for (int q = 0; q < 12; ++q) {
        float4 v; v.x = acc[q*4+0]; v.y = acc[q*4+1]; v.z = acc[q*4+2]; v.w = acc[q*4+3];
        ((float4*)dst)[q] = v;
    }
}

// ---------------------------------------------------------------------------

extern "C" void kernel_launch(void* const* d_in, const int* in_sizes, int n_in,
                              void* d_out, int out_size, void* d_ws, size_t ws_size,
                              hipStream_t stream) {
    (void)in_sizes; (void)n_in; (void)out_size; (void)ws_size;
    const float* frame    = (const float*)d_in[0];
    const float* srcframe = (const float*)d_in[1];
    const float* flow_f   = (const float*)d_in[2];
    const float* flow_b   = (const float*)d_in[3];
    const float* w_qk  = (const float*)d_in[4];  const float* b_qk  = (const float*)d_in[5];
    const float* w_v   = (const float*)d_in[6];  const float* b_v   = (const float*)d_in[7];
    const float* w_vp  = (const float*)d_in[8];  const float* b_vp  = (const float*)d_in[9];
    const float* w_off = (const float*)d_in[10]; const float* b_off = (const float*)d_in[11];
    const float* w_at  = (const float*)d_in[12]; const float* b_at  = (const float*)d_in[13];
    const float* w_out = (const float*)d_in[14]; const float* b_out = (const float*)d_in[15];
    const float* w_ff  = (const float*)d_in[16]; const float* b_ff  = (const float*)d_in[17];
    const float* w_f1  = (const float*)d_in[18]; const float* b_f1  = (const float*)d_in[19];
    const float* w_f2  = (const float*)d_in[20]; const float* b_f2  = (const float*)d_in[21];
    float* out = (float*)d_out;
    float* ws  = (float*)d_ws;

    // workspace layout (floats); total 49,364,992 floats = 197.5 MB
    float* flows   = ws + 0;              // 81920
    float* qkin    = ws + 81920;          // 7,995,392  (reused as acc)
    float* Q       = ws + 8077312;        // 7,864,320  (reused as ffn_mid)
    float* V       = ws + 15941632;       // 7,864,320  (reused as attn_sp)
    float* vp      = ws + 23805952;       // 7,864,320
    float* offs    = ws + 31670272;       // 6,553,600
    float* aw      = ws + 38223872;       // 3,276,800
    float* out1    = ws + 41500672;       // 7,864,320
    float* acc     = qkin;
    float* attn_sp = V;
    float* ffn_mid = Q;

    // 1. flow composition
    k_flow<<<32, 256, 0, stream>>>(flow_f, flow_b, flows);
    // 2. qk_in assembly (warps + copies)
    k_qkin<<<dim3(16, CIQK, BB), 256, 0, stream>>>(frame, flow_f, flow_b, flows, qkin);
    // 3. conv_qk: (B,976,HW) -> queries (B,960,HW), leaky
    k_conv3<CIQK,1,true,false><<<dim3(15,32,BB), 256, 0, stream>>>(
        qkin, (long)CIQK*HWPX, nullptr, 0, CIQK, w_qk, b_qk, nullptr, Q, TC);
    // 4. conv_v: frame (B,960,HW) -> value (B,960,HW), leaky
    k_conv3<TC,1,true,false><<<dim3(15,32,BB), 256, 0, stream>>>(
        frame, (long)TC*HWPX, nullptr, 0, TC, w_v, b_v, nullptr, V, TC);
    // 5. v_proj: per (b,t) 192x192 GEMM -> vp (B,T,NH,HW,DH) token-major
    k_gemm<1><<<dim3(3,32,BB*TT), 256, 0, stream>>>(
        V, (long)CCH*HWPX, HWPX, 1, w_vp, b_vp, nullptr, nullptr, CCH, CCH,
        vp, (long)TT*CCH*HWPX, (long)CCH*HWPX, 0, nullptr, 0, 0, 0);
    // 6. offsets (160) + attn logits (80): fused GEMM, CO=240
    k_gemm<0><<<dim3(4,32,BB*TT), 256, 0, stream>>>(
        Q, (long)CCH*HWPX, HWPX, 1, w_off, b_off, w_at, b_at, 160, 240,
        offs, (long)160*LQ, (long)HWPX, LQ, aw, (long)80*LQ, (long)HWPX, LQ);
    // 7. softmax over 20 (NL*NP) per (b,lq,head)
    k_softmax20<<<640, 256, 0, stream>>>(aw);
    // 8. deformable sampling + weighted sum -> acc (B,LQ,192) token-major
    k_sample<<<640, 256, 0, stream>>>(vp, offs, aw, flows, acc);
    // 9. output projection: acc @ w_out.T -> attn_sp (B*T,192,HW) channel-major
    k_gemm<0><<<dim3(3,32,BB*TT), 256, 0, stream>>>(
        acc, (long)CCH*HWPX, 1, CCH, w_out, b_out, nullptr, nullptr, CCH, CCH,
        attn_sp, (long)TT*CCH*HWPX, (long)CCH*HWPX, HWPX, nullptr, 0, 0, 0);
    // 10. conv_ff + frame residual -> out1
    k_conv3<CCH,1,false,true><<<dim3(3,32,BB*TT), 256, 0, stream>>>(
        attn_sp, (long)CCH*HWPX, nullptr, 0, CCH, w_ff, b_ff, frame, out1, CCH);
    // 11. ffn1: concat(out1, srcframe) 384ch, dilation 2, leaky -> ffn_mid
    k_conv3<2*CCH,2,true,false><<<dim3(3,32,BB*TT), 256, 0, stream>>>(
        out1, (long)CCH*HWPX, srcframe, (long)CCH*HWPX, CCH, w_f1, b_f1, nullptr, ffn_mid, CCH);
    // 12. ffn2 + out1 residual -> d_out (first half)
    k_conv3<CCH,1,false,true><<<dim3(3,32,BB*TT), 256, 0, stream>>>(
        ffn_mid, (long)CCH*HWPX, nullptr, 0, CCH, w_f2, b_f2, out1, out, CCH);
    // 13. second output = srcframe passthrough
    hipMemcpyAsync(out + (long)BB*TT*CCH*HWPX, srcframe,
                   (size_t)BB*TT*CCH*HWPX*sizeof(float),
                   hipMemcpyDeviceToDevice, stream);
}

// Round 2
// 1623.399 us; speedup vs baseline: 10.1731x; 10.1731x over previous
//
#include <hip/hip_runtime.h>

// ---------------------------------------------------------------------------
// DeformableAttnBlock — round 2: all 3x3 convs -> bf16 MFMA implicit GEMM
// B=2, T=5, C=192, H=W=64, NH=4, NL=5, NP=4, DH=48
// ---------------------------------------------------------------------------

#define HWPX 4096
#define WX   64
#define TT   5
#define CCH  192
#define TC   960
#define CIQK 976
#define LQ   20480
#define NHH  4
#define NLL  5
#define NPP  4
#define DHH  48
#define BB   2

typedef __attribute__((ext_vector_type(8))) short  short8;
typedef __attribute__((ext_vector_type(4))) float  f32x4;

__device__ __forceinline__ unsigned short f2bf(float f) {
    unsigned u = __float_as_uint(f);
    unsigned r = (u + 0x7FFF + ((u >> 16) & 1)) >> 16;   // RNE
    return (unsigned short)r;
}

// bilinear sample with border clamp (grid_sample_border semantics)
__device__ __forceinline__ float bsample(const float* __restrict__ p, float sx, float sy) {
    sx = fminf(fmaxf(sx, 0.f), 63.f);
    sy = fminf(fmaxf(sy, 0.f), 63.f);
    float x0 = floorf(sx), y0 = floorf(sy);
    int ix0 = (int)x0, iy0 = (int)y0;
    int ix1 = ix0 < 63 ? ix0 + 1 : 63;
    int iy1 = iy0 < 63 ? iy0 + 1 : 63;
    float wx = sx - x0, wy = sy - y0;
    float v00 = p[iy0*WX+ix0], v01 = p[iy0*WX+ix1];
    float v10 = p[iy1*WX+ix0], v11 = p[iy1*WX+ix1];
    return (v00*(1.f-wx) + v01*wx)*(1.f-wy) + (v10*(1.f-wx) + v11*wx)*wy;
}

// K1: flow composition. flows layout (B, 5, 2, HW)
__global__ __launch_bounds__(256) void k_flow(const float* __restrict__ ff,
                                              const float* __restrict__ fb,
                                              float* __restrict__ flows) {
    int i = blockIdx.x*256 + threadIdx.x;
    int b = i >> 12, pix = i & 4095;
    int x = pix & 63, y = pix >> 6;
    const float* ff01 = ff + (size_t)(b*4+0)*2*HWPX;
    const float* ff12 = ff + (size_t)(b*4+1)*2*HWPX;
    const float* fb32 = fb + (size_t)(b*4+2)*2*HWPX;
    const float* fb43 = fb + (size_t)(b*4+3)*2*HWPX;
    float* F = flows + (size_t)b*NLL*2*HWPX;
    float ax = ff01[pix], ay = ff01[HWPX+pix];
    float sx = bsample(ff12,      (float)x+ax, (float)y+ay);
    float sy = bsample(ff12+HWPX, (float)x+ax, (float)y+ay);
    F[0*2*HWPX + pix]        = ax + sx;
    F[0*2*HWPX + HWPX + pix] = ay + sy;
    F[1*2*HWPX + pix]        = ff12[pix];
    F[1*2*HWPX + HWPX + pix] = ff12[HWPX+pix];
    F[2*2*HWPX + pix]        = 0.f;
    F[2*2*HWPX + HWPX + pix] = 0.f;
    F[3*2*HWPX + pix]        = fb32[pix];
    F[3*2*HWPX + HWPX + pix] = fb32[HWPX+pix];
    float bx = fb43[pix], by = fb43[HWPX+pix];
    float tx = bsample(fb32,      (float)x+bx, (float)y+by);
    float ty = bsample(fb32+HWPX, (float)x+bx, (float)y+by);
    F[4*2*HWPX + pix]        = bx + tx;
    F[4*2*HWPX + HWPX + pix] = by + ty;
}

// K2: assemble qk_in (B, 976, HW)
__global__ __launch_bounds__(256) void k_qkin(const float* __restrict__ frame,
                                              const float* __restrict__ ff,
                                              const float* __restrict__ fb,
                                              const float* __restrict__ flows,
                                              float* __restrict__ qk) {
    int pix = blockIdx.x*256 + threadIdx.x;
    int c = blockIdx.y, b = blockIdx.z;
    float* dst = qk + ((size_t)b*CIQK + c)*HWPX + pix;
    if (c >= TC) {
        int k = c - TC;
        const float* src = (k < 8) ? ff + (size_t)(b*8+k)*HWPX : fb + (size_t)(b*8+k-8)*HWPX;
        *dst = src[pix];
        return;
    }
    int slot = c / CCH, cc = c % CCH;
    const float* plane = frame + ((size_t)(b*TT+slot)*CCH + cc)*HWPX;
    if (slot == 2) { *dst = plane[pix]; return; }
    const float* F = flows + ((size_t)(b*NLL+slot)*2)*HWPX;
    float fx = F[pix], fy = F[HWPX+pix];
    int x = pix & 63, y = pix >> 6;
    *dst = bsample(plane, (float)x+fx, (float)y+fy);
}

// T1: weight transform  w[CO][CI][3][3] fp32 -> wT[tap][CO][CIP] bf16 (zero-padded)
__global__ __launch_bounds__(256) void t_wT(const float* __restrict__ w,
                                            unsigned short* __restrict__ wT,
                                            int CI, int CIP, int CO) {
    __shared__ float s[8784];            // up to CI=976 * 9
    int co = blockIdx.x, tid = threadIdx.x;
    int n = CI*9;
    for (int li = tid; li < n; li += 256) s[li] = w[(size_t)co*n + li];
    __syncthreads();
    int chunks = 9*(CIP>>3);
    for (int li = tid; li < chunks; li += 256) {
        int tap = li / (CIP>>3);
        int ci0 = (li % (CIP>>3)) * 8;
        unsigned short v[8];
        #pragma unroll
        for (int j = 0; j < 8; ++j) {
            int ci = ci0 + j;
            v[j] = (ci < CI) ? f2bf(s[ci*9 + tap]) : (unsigned short)0;
        }
        unsigned short* dst = wT + ((size_t)tap*CO + co)*CIP + ci0;
        *(short8*)dst = *(const short8*)v;
    }
}

// T2: input transform  in[img][CItot][4096] fp32 (optional 2-src concat)
//     -> xbf[img][4096][CIP] bf16 (zero-padded)
__global__ __launch_bounds__(256) void t_x(const float* __restrict__ in1, long str1,
                                           const float* __restrict__ in2, long str2,
                                           int CI1, int CItot, int CIP,
                                           unsigned short* __restrict__ xbf) {
    __shared__ float s[64][65];
    int tid = threadIdx.x;
    int px0 = blockIdx.x * 64, img = blockIdx.y;
    const float* i1 = in1 + (size_t)img*str1;
    const float* i2 = in2 ? in2 + (size_t)img*str2 : nullptr;
    unsigned short* ob = xbf + (size_t)img*4096*CIP;
    for (int ci0 = 0; ci0 < CIP; ci0 += 64) {
        for (int li = tid; li < 4096; li += 256) {
            int cl = li >> 6, pl = li & 63;
            int cg = ci0 + cl;
            float v = 0.f;
            if (cg < CI1)        v = i1[(size_t)cg*HWPX + px0 + pl];
            else if (cg < CItot) v = i2[(size_t)(cg-CI1)*HWPX + px0 + pl];
            s[cl][pl] = v;
        }
        __syncthreads();
        for (int li = tid; li < 512; li += 256) {
            int pl = li >> 3, c = li & 7;
            int cib = ci0 + c*8;
            if (cib < CIP) {
                unsigned short v[8];
                #pragma unroll
                for (int j = 0; j < 8; ++j) v[j] = f2bf(s[c*8 + j][pl]);
                *(short8*)(ob + (size_t)(px0 + pl)*CIP + cib) = *(const short8*)v;
            }
        }
        __syncthreads();
    }
}

// K3: MFMA implicit-GEMM 3x3 conv.
// xbf: [img][4096][CIP] bf16, wT: [tap][CO][CIP] bf16, out: [img][CO][4096] fp32
// block: 64 co x (4 rows x 64 px); wave w handles row w; per-wave 4x4 16x16 frags.
template<int DIL, bool LEAKY, bool RES>
__global__ __launch_bounds__(256) void k_convmfma(
    const unsigned short* __restrict__ xbf, const unsigned short* __restrict__ wT,
    const float* __restrict__ bias, const float* __restrict__ res,
    float* __restrict__ out, int CIP, int CO)
{
    constexpr int RR = 4 + 2*DIL;        // staged rows
    constexpr int XP = 64 + 2*DIL;       // staged cols
    __shared__ unsigned short s_x[RR][XP][40];   // 32 ci + 8 pad (80B px stride)
    int tid = threadIdx.x;
    int cotile = blockIdx.x, pxt = blockIdx.y, img = blockIdx.z;
    int w = tid >> 6, lane = tid & 63;
    int lm = lane & 15, cig = lane >> 4;
    int y0 = pxt * 4;
    const unsigned short* xb = xbf + (size_t)img*4096*CIP;
    f32x4 acc[4][4] = {};

    for (int k0 = 0; k0 < CIP; k0 += 32) {
        // stage input tile (bf16, 32 ci), zero-padded halo
        for (int li = tid; li < RR*XP*4; li += 256) {
            int r = li / (XP*4); int rem = li % (XP*4);
            int x = rem >> 2, c = rem & 3;
            int gy = y0 - DIL + r, gx = x - DIL;
            short8 v = {};
            if (gy >= 0 && gy < 64 && gx >= 0 && gx < 64)
                v = *(const short8*)(xb + ((size_t)((gy<<6)+gx))*CIP + k0 + c*8);
            *(short8*)&s_x[r][x][c*8] = v;
        }
        __syncthreads();
        const unsigned short* wbase = wT + k0 + cig*8;
        #pragma unroll
        for (int t = 0; t < 9; ++t) {
            int ky = t/3, kx = t%3;
            short8 b[4], a[4];
            #pragma unroll
            for (int nb = 0; nb < 4; ++nb)
                b[nb] = *(const short8*)&s_x[w + ky*DIL][nb*16 + lm + kx*DIL][cig*8];
            #pragma unroll
            for (int mb = 0; mb < 4; ++mb) {
                int co = cotile*64 + mb*16 + lm;
                a[mb] = *(const short8*)(wbase + ((size_t)t*CO + co)*CIP);
            }
            #pragma unroll
            for (int mb = 0; mb < 4; ++mb)
                #pragma unroll
                for (int nb = 0; nb < 4; ++nb)
                    acc[mb][nb] = __builtin_amdgcn_mfma_f32_16x16x32_bf16(
                        a[mb], b[nb], acc[mb][nb], 0, 0, 0);
        }
        __syncthreads();
    }
    // epilogue: C/D layout col=lane&15 (px), row=(lane>>4)*4+reg (co)
    int y = y0 + w;
    #pragma unroll
    for (int mb = 0; mb < 4; ++mb) {
        int cob = cotile*64 + mb*16 + cig*4;
        #pragma unroll
        for (int nb = 0; nb < 4; ++nb) {
            int x = nb*16 + lm;
            #pragma unroll
            for (int r = 0; r < 4; ++r) {
                int c2 = cob + r;
                float v = acc[mb][nb][r] + bias[c2];
                if (LEAKY) v = v >= 0.f ? v : 0.1f*v;
                long o = ((long)img*CO + c2)*HWPX + (y<<6) + x;
                if (RES) v += res[o];
                out[o] = v;
            }
        }
    }
}

// K4/6/9: skinny fp32 GEMM (K=192)
template<int TOK48>
__global__ __launch_bounds__(256) void k_gemm(
    const float* __restrict__ in, long in_img_str, int ci_stride, int px_stride,
    const float* __restrict__ w1, const float* __restrict__ bias1,
    const float* __restrict__ w2, const float* __restrict__ bias2,
    int co_split, int CO,
    float* __restrict__ out1, long o1b, long o1t, long o1row,
    float* __restrict__ out2, long o2b, long o2t, long o2row)
{
    __shared__ float s_in[8][128];
    __shared__ float s_w[64][8];
    int tid = threadIdx.x;
    int cotile = blockIdx.x, pxt = blockIdx.y, img = blockIdx.z;
    int px0 = pxt*128;
    int pxg = tid & 31, cog = tid >> 5;
    const float* inb = in + (size_t)img*in_img_str;
    float acc[8][4] = {};

    for (int k0 = 0; k0 < 192; k0 += 8) {
        if (px_stride == 1) {
            int ci = tid >> 5, tok = (tid & 31) * 4;
            float4 v = *(const float4*)(inb + (long)(k0+ci)*ci_stride + px0 + tok);
            ((float4*)s_in[ci])[tok>>2] = v;
        } else {
            int tok = tid >> 1, u = (tid & 1)*4;
            float4 v = *(const float4*)(inb + (long)(px0+tok)*px_stride + k0 + u);
            s_in[u+0][tok] = v.x; s_in[u+1][tok] = v.y;
            s_in[u+2][tok] = v.z; s_in[u+3][tok] = v.w;
        }
        #pragma unroll
        for (int q = 0; q < 2; ++q) {
            int li = tid + q*256;
            int co = li >> 3, ci = li & 7;
            int cg = cotile*64 + co;
            float v = 0.f;
            if (cg < CO) {
                const float* row = (cg < co_split) ? w1 + (long)cg*192
                                                   : w2 + (long)(cg - co_split)*192;
                v = row[k0 + ci];
            }
            s_w[co][ci] = v;
        }
        __syncthreads();
        #pragma unroll
        for (int ci = 0; ci < 8; ++ci) {
            float4 a = ((const float4*)s_in[ci])[pxg];
            #pragma unroll
            for (int i = 0; i < 8; ++i) {
                float wv = s_w[cog*8+i][ci];
                acc[i][0] += wv*a.x; acc[i][1] += wv*a.y;
                acc[i][2] += wv*a.z; acc[i][3] += wv*a.w;
            }
        }
        __syncthreads();
    }
    int b = img / TT, t = img % TT;
    #pragma unroll
    for (int i = 0; i < 8; ++i) {
        int co = cotile*64 + cog*8 + i;
        if (co >= CO) break;
        float bv = (co < co_split) ? bias1[co] : bias2[co - co_split];
        #pragma unroll
        for (int j = 0; j < 4; ++j) {
            float v = acc[i][j] + bv;
            int px = px0 + pxg*4 + j;
            if (TOK48) {
                out1[(long)b*o1b + (long)t*o1t + (long)(co/48)*(48*HWPX) + (long)px*48 + (co%48)] = v;
            } else if (co < co_split) {
                out1[(long)b*o1b + (long)t*o1t + (long)co*o1row + px] = v;
            } else {
                out2[(long)b*o2b + (long)t*o2t + (long)(co - co_split)*o2row + px] = v;
            }
        }
    }
}

// K7: softmax over 20 values at stride LQ
__global__ __launch_bounds__(256) void k_softmax20(float* __restrict__ aw) {
    int i = blockIdx.x*256 + threadIdx.x;
    int lq = i % LQ;
    int bh = i / LQ;
    float* p = aw + (long)bh*20*LQ + lq;
    float e[20];
    float m = -1e30f;
    #pragma unroll
    for (int j = 0; j < 20; ++j) { e[j] = p[j*LQ]; m = fmaxf(m, e[j]); }
    float s = 0.f;
    #pragma unroll
    for (int j = 0; j < 20; ++j) { e[j] = expf(e[j]-m); s += e[j]; }
    float inv = 1.f/s;
    #pragma unroll
    for (int j = 0; j < 20; ++j) p[j*LQ] = e[j]*inv;
}

__device__ __forceinline__ void addtap(float* acc, const float* __restrict__ src, float w) {
    const float4* s4 = (const float4*)src;
    #pragma unroll
    for (int q = 0; q < 12; ++q) {
        float4 v = s4[q];
        acc[q*4+0] += w*v.x; acc[q*4+1] += w*v.y;
        acc[q*4+2] += w*v.z; acc[q*4+3] += w*v.w;
    }
}

// K8: deformable sampling + weighted accumulation
__global__ __launch_bounds__(256) void k_sample(
    const float* __restrict__ vp, const float* __restrict__ offs,
    const float* __restrict__ aw, const float* __restrict__ flows,
    float* __restrict__ accout)
{
    int blk = blockIdx.x;
    int b = blk / 320, sub = blk % 320;
    int h = threadIdx.x >> 6;
    int lq = sub*64 + (threadIdx.x & 63);
    int pix = lq % HWPX;
    int x = pix & 63, y = pix >> 6;
    const float* offp = offs + ((long)b*160 + h*40)*LQ + lq;
    const float* awp  = aw   + ((long)b*80  + h*20)*LQ + lq;
    float acc[48];
    #pragma unroll
    for (int d = 0; d < 48; ++d) acc[d] = 0.f;

    for (int l = 0; l < NLL; ++l) {
        float fx = flows[((long)(b*NLL+l)*2+0)*HWPX + pix];
        float fy = flows[((long)(b*NLL+l)*2+1)*HWPX + pix];
        const float* vpl = vp + ((long)(b*TT+l)*NHH + h)*HWPX*DHH;
        #pragma unroll
        for (int p = 0; p < NPP; ++p) {
            int o = l*4 + p;
            float ox = offp[(long)(2*o)*LQ];
            float oy = offp[(long)(2*o+1)*LQ];
            float wv = awp[(long)o*LQ];
            float sx = (float)x + ox + fx;
            float sy = (float)y + oy + fy;
            float x0f = floorf(sx), y0f = floorf(sy);
            float wx = sx - x0f, wy = sy - y0f;
            int ix0 = (int)x0f, iy0 = (int)y0f;
            float w00 = wv*(1.f-wx)*(1.f-wy), w01 = wv*wx*(1.f-wy);
            float w10 = wv*(1.f-wx)*wy,       w11 = wv*wx*wy;
            bool vx0 = (ix0 >= 0)  && (ix0 <= 63);
            bool vx1 = (ix0 >= -1) && (ix0 <= 62);
            bool vy0 = (iy0 >= 0)  && (iy0 <= 63);
            bool vy1 = (iy0 >= -1) && (iy0 <= 62);
            if (vy0 && vx0) addtap(acc, vpl + (long)(iy0*WX + ix0)*DHH,       w00);
            if (vy0 && vx1) addtap(acc, vpl + (long)(iy0*WX + ix0 + 1)*DHH,   w01);
            if (vy1 && vx0) addtap(acc, vpl + (long)((iy0+1)*WX + ix0)*DHH,   w10);
            if (vy1 && vx1) addtap(acc, vpl + (long)((iy0+1)*WX + ix0+1)*DHH, w11);
        }
    }
    float* dst = accout + ((long)b*LQ + lq)*CCH + h*DHH;
    #pragma unroll
    for (int q = 0; q < 12; ++q) {
        float4 v; v.x = acc[q*4+0]; v.y = acc[q*4+1]; v.z = acc[q*4+2]; v.w = acc[q*4+3];
        ((float4*)dst)[q] = v;
    }
}

// ---------------------------------------------------------------------------

extern "C" void kernel_launch(void* const* d_in, const int* in_sizes, int n_in,
                              void* d_out, int out_size, void* d_ws, size_t ws_size,
                              hipStream_t stream) {
    (void)in_sizes; (void)n_in; (void)out_size; (void)ws_size;
    const float* frame    = (const float*)d_in[0];
    const float* srcframe = (const float*)d_in[1];
    const float* flow_f   = (const float*)d_in[2];
    const float* flow_b   = (const float*)d_in[3];
    const float* w_qk  = (const float*)d_in[4];  const float* b_qk  = (const float*)d_in[5];
    const float* w_v   = (const float*)d_in[6];  const float* b_v   = (const float*)d_in[7];
    const float* w_vp  = (const float*)d_in[8];  const float* b_vp  = (const float*)d_in[9];
    const float* w_off = (const float*)d_in[10]; const float* b_off = (const float*)d_in[11];
    const float* w_at  = (const float*)d_in[12]; const float* b_at  = (const float*)d_in[13];
    const float* w_out = (const float*)d_in[14]; const float* b_out = (const float*)d_in[15];
    const float* w_ff  = (const float*)d_in[16]; const float* b_ff  = (const float*)d_in[17];
    const float* w_f1  = (const float*)d_in[18]; const float* b_f1  = (const float*)d_in[19];
    const float* w_f2  = (const float*)d_in[20]; const float* b_f2  = (const float*)d_in[21];
    float* out = (float*)d_out;
    float* ws  = (float*)d_ws;

    // workspace layout (floats) — identical footprint to round 0 (197.5 MB)
    float* flows   = ws + 0;              // A: 81920
    float* qkin    = ws + 81920;          // B: 7,995,392  (→ acc, → xbf_sm)
    float* Q       = ws + 8077312;        // C: 7,864,320  (→ ffn_mid)
    float* V       = ws + 15941632;       // D: 7,864,320  (wT_qk → V → attn_sp)
    float* vp      = ws + 23805952;       // E: 7,864,320  (wT_v → vp)
    float* offs    = ws + 31670272;       // F: 6,553,600  (offs → wT_sm)
    float* aw      = ws + 38223872;       // G: 3,276,800
    float* out1    = ws + 41500672;       // H: 7,864,320  (xbf_big → out1)
    float* acc     = qkin;
    float* attn_sp = V;
    float* ffn_mid = Q;
    unsigned short* wT_qk   = (unsigned short*)V;       // 17.1 MB, dead before V written
    unsigned short* wT_v    = (unsigned short*)vp;      // 16.6 MB, dead before vp written
    unsigned short* wT_sm   = (unsigned short*)offs;    // ≤1.4 MB, after offs dead
    unsigned short* xbf_big = (unsigned short*)out1;    // ≤16.3 MB, dead before out1 written
    unsigned short* xbf_sm  = (unsigned short*)qkin;    // ≤31.5 MB, after qkin/acc dead

    // 1. flow composition
    k_flow<<<32, 256, 0, stream>>>(flow_f, flow_b, flows);
    // 2. qk_in assembly (fp32 channel-major)
    k_qkin<<<dim3(16, CIQK, BB), 256, 0, stream>>>(frame, flow_f, flow_b, flows, qkin);
    // 3. conv_qk via MFMA: transform weights + input, then conv
    t_wT<<<TC, 256, 0, stream>>>(w_qk, wT_qk, CIQK, 992, TC);
    t_x<<<dim3(64, BB), 256, 0, stream>>>(qkin, (long)CIQK*HWPX, nullptr, 0, CIQK, CIQK, 992, xbf_big);
    k_convmfma<1,true,false><<<dim3(15,16,BB), 256, 0, stream>>>(
        xbf_big, wT_qk, b_qk, nullptr, Q, 992, TC);
    // 4. conv_v via MFMA
    t_wT<<<TC, 256, 0, stream>>>(w_v, wT_v, TC, TC, TC);
    t_x<<<dim3(64, BB), 256, 0, stream>>>(frame, (long)TC*HWPX, nullptr, 0, TC, TC, TC, xbf_big);
    k_convmfma<1,true,false><<<dim3(15,16,BB), 256, 0, stream>>>(
        xbf_big, wT_v, b_v, nullptr, V, TC, TC);
    // 5. v_proj -> vp (B,T,NH,HW,DH) token-major
    k_gemm<1><<<dim3(3,32,BB*TT), 256, 0, stream>>>(
        V, (long)CCH*HWPX, HWPX, 1, w_vp, b_vp, nullptr, nullptr, CCH, CCH,
        vp, (long)TT*CCH*HWPX, (long)CCH*HWPX, 0, nullptr, 0, 0, 0);
    // 6. offsets + attn logits fused GEMM
    k_gemm<0><<<dim3(4,32,BB*TT), 256, 0, stream>>>(
        Q, (long)CCH*HWPX, HWPX, 1, w_off, b_off, w_at, b_at, 160, 240,
        offs, (long)160*LQ, (long)HWPX, LQ, aw, (long)80*LQ, (long)HWPX, LQ);
    // 7. softmax
    k_softmax20<<<640, 256, 0, stream>>>(aw);
    // 8. deformable sampling -> acc (token-major)
    k_sample<<<640, 256, 0, stream>>>(vp, offs, aw, flows, acc);
    // 9. output projection -> attn_sp (channel-major)
    k_gemm<0><<<dim3(3,32,BB*TT), 256, 0, stream>>>(
        acc, (long)CCH*HWPX, 1, CCH, w_out, b_out, nullptr, nullptr, CCH, CCH,
        attn_sp, (long)TT*CCH*HWPX, (long)CCH*HWPX, HWPX, nullptr, 0, 0, 0);
    // 10. conv_ff + frame residual -> out1
    t_wT<<<CCH, 256, 0, stream>>>(w_ff, wT_sm, CCH, CCH, CCH);
    t_x<<<dim3(64, BB*TT), 256, 0, stream>>>(attn_sp, (long)CCH*HWPX, nullptr, 0, CCH, CCH, CCH, xbf_sm);
    k_convmfma<1,false,true><<<dim3(3,16,BB*TT), 256, 0, stream>>>(
        xbf_sm, wT_sm, b_ff, frame, out1, CCH, CCH);
    // 11. ffn1: concat(out1, srcframe), dilation 2, leaky -> ffn_mid
    t_wT<<<CCH, 256, 0, stream>>>(w_f1, wT_sm, 2*CCH, 2*CCH, CCH);
    t_x<<<dim3(64, BB*TT), 256, 0, stream>>>(out1, (long)CCH*HWPX, srcframe, (long)CCH*HWPX,
                                             CCH, 2*CCH, 2*CCH, xbf_sm);
    k_convmfma<2,true,false><<<dim3(3,16,BB*TT), 256, 0, stream>>>(
        xbf_sm, wT_sm, b_f1, nullptr, ffn_mid, 2*CCH, CCH);
    // 12. ffn2 + out1 residual -> d_out
    t_wT<<<CCH, 256, 0, stream>>>(w_f2, wT_sm, CCH, CCH, CCH);
    t_x<<<dim3(64, BB*TT), 256, 0, stream>>>(ffn_mid, (long)CCH*HWPX, nullptr, 0, CCH, CCH, CCH, xbf_sm);
    k_convmfma<1,false,true><<<dim3(3,16,BB*TT), 256, 0, stream>>>(
        xbf_sm, wT_sm, b_f2, out1, out, CCH, CCH);
    // 13. second output = srcframe passthrough
    hipMemcpyAsync(out + (long)BB*TT*CCH*HWPX, srcframe,
                   (size_t)BB*TT*CCH*HWPX*sizeof(float),
                   hipMemcpyDeviceToDevice, stream);
}

// Round 3
// 1011.787 us; speedup vs baseline: 16.3226x; 1.6045x over previous
//
#include <hip/hip_runtime.h>

// ---------------------------------------------------------------------------
// DeformableAttnBlock — round 3: MFMA everywhere, bf16 token-major pipeline.
// B=2, T=5, C=192, H=W=64, NH=4, NL=5, NP=4, DH=48
// Padded images: 68x68 (pad=2), token-major bf16, channel-count mult of 32.
// ---------------------------------------------------------------------------

#define HWPX 4096
#define PPXN 4624      // 68*68
#define LQ   20480

typedef __attribute__((ext_vector_type(8))) short  short8;
typedef __attribute__((ext_vector_type(4))) short  short4v;
typedef __attribute__((ext_vector_type(4))) float  f32x4;

__device__ __forceinline__ unsigned short f2bf(float f) {
    unsigned u = __float_as_uint(f);
    unsigned r = (u + 0x7FFF + ((u >> 16) & 1)) >> 16;   // RNE
    return (unsigned short)r;
}
__device__ __forceinline__ float bf2f(unsigned short s) {
    return __uint_as_float(((unsigned)s) << 16);
}

__device__ __forceinline__ void gl_lds16(const unsigned short* g, unsigned short* l) {
    __builtin_amdgcn_global_load_lds(
        (const __attribute__((address_space(1))) unsigned int*)g,
        (__attribute__((address_space(3))) unsigned int*)l, 16, 0, 0);
}

// ---------------------------------------------------------------------------
// K1: flow composition. flows layout (B, 5, 2, HW): l0=ff02,l1=ff12,l2=0,l3=fb32,l4=fb42
__device__ __forceinline__ float bsample(const float* __restrict__ p, float sx, float sy) {
    sx = fminf(fmaxf(sx, 0.f), 63.f);
    sy = fminf(fmaxf(sy, 0.f), 63.f);
    float x0 = floorf(sx), y0 = floorf(sy);
    int ix0 = (int)x0, iy0 = (int)y0;
    int ix1 = ix0 < 63 ? ix0 + 1 : 63;
    int iy1 = iy0 < 63 ? iy0 + 1 : 63;
    float wx = sx - x0, wy = sy - y0;
    float v00 = p[iy0*64+ix0], v01 = p[iy0*64+ix1];
    float v10 = p[iy1*64+ix0], v11 = p[iy1*64+ix1];
    return (v00*(1.f-wx) + v01*wx)*(1.f-wy) + (v10*(1.f-wx) + v11*wx)*wy;
}

__global__ __launch_bounds__(256) void k_flow(const float* __restrict__ ff,
                                              const float* __restrict__ fb,
                                              float* __restrict__ flows) {
    int i = blockIdx.x*256 + threadIdx.x;
    int b = i >> 12, pix = i & 4095;
    int x = pix & 63, y = pix >> 6;
    const float* ff01 = ff + (size_t)(b*4+0)*2*HWPX;
    const float* ff12 = ff + (size_t)(b*4+1)*2*HWPX;
    const float* fb32 = fb + (size_t)(b*4+2)*2*HWPX;
    const float* fb43 = fb + (size_t)(b*4+3)*2*HWPX;
    float* F = flows + (size_t)b*5*2*HWPX;
    float ax = ff01[pix], ay = ff01[HWPX+pix];
    float sx = bsample(ff12,      (float)x+ax, (float)y+ay);
    float sy = bsample(ff12+HWPX, (float)x+ax, (float)y+ay);
    F[0*2*HWPX + pix]        = ax + sx;
    F[0*2*HWPX + HWPX + pix] = ay + sy;
    F[1*2*HWPX + pix]        = ff12[pix];
    F[1*2*HWPX + HWPX + pix] = ff12[HWPX+pix];
    F[2*2*HWPX + pix]        = 0.f;
    F[2*2*HWPX + HWPX + pix] = 0.f;
    F[3*2*HWPX + pix]        = fb32[pix];
    F[3*2*HWPX + HWPX + pix] = fb32[HWPX+pix];
    float bx = fb43[pix], by = fb43[HWPX+pix];
    float tx = bsample(fb32,      (float)x+bx, (float)y+by);
    float ty = bsample(fb32+HWPX, (float)x+bx, (float)y+by);
    F[4*2*HWPX + pix]        = bx + tx;
    F[4*2*HWPX + HWPX + pix] = by + ty;
}

// ---------------------------------------------------------------------------
// K2: fused qk_in assembly: warp + pad + bf16 pack -> P_qk [b][4624][992]
// block (64,4): tx = ppx lane, ty = c8 quad. grid (73, 31, 2)
__global__ void k_qkin(const float* __restrict__ frame, const float* __restrict__ ff,
                       const float* __restrict__ fb, const float* __restrict__ flows,
                       unsigned short* __restrict__ Pqk)
{
    int ppx = blockIdx.x*64 + threadIdx.x;
    if (ppx >= PPXN) return;
    int b = blockIdx.z;
    int c8 = (blockIdx.y*4 + threadIdx.y)*8;
    unsigned short* dst = Pqk + ((size_t)b*PPXN + ppx)*992 + c8;
    int py = ppx/68, pxc = ppx - py*68;
    short8 o = {};
    if (py >= 2 && py < 66 && pxc >= 2 && pxc < 66 && c8 < 976) {
        int y = py-2, x = pxc-2, pix = (y<<6)+x;
        if (c8 >= 960) {
            #pragma unroll
            for (int j = 0; j < 8; ++j) {
                int k = c8 - 960 + j;
                float v = (k < 8) ? ff[((size_t)b*8 + k)*HWPX + pix]
                                  : fb[((size_t)b*8 + k - 8)*HWPX + pix];
                o[j] = (short)f2bf(v);
            }
        } else {
            int slot = c8/192, cc = c8 - slot*192;
            const float* base = frame + ((size_t)(b*5 + slot)*192)*HWPX;
            if (slot == 2) {
                #pragma unroll
                for (int j = 0; j < 8; ++j)
                    o[j] = (short)f2bf(base[(size_t)(cc+j)*HWPX + pix]);
            } else {
                const float* F = flows + ((size_t)(b*5 + slot)*2)*HWPX;
                float sx = fminf(fmaxf((float)x + F[pix], 0.f), 63.f);
                float sy = fminf(fmaxf((float)y + F[HWPX + pix], 0.f), 63.f);
                float x0 = floorf(sx), y0 = floorf(sy);
                int ix0 = (int)x0, iy0 = (int)y0;
                int ix1 = ix0 < 63 ? ix0+1 : 63, iy1 = iy0 < 63 ? iy0+1 : 63;
                float wx = sx - x0, wy = sy - y0;
                float w00 = (1.f-wx)*(1.f-wy), w01 = wx*(1.f-wy);
                float w10 = (1.f-wx)*wy,       w11 = wx*wy;
                int i00 = iy0*64+ix0, i01 = iy0*64+ix1;
                int i10 = iy1*64+ix0, i11 = iy1*64+ix1;
                #pragma unroll
                for (int j = 0; j < 8; ++j) {
                    const float* p = base + (size_t)(cc+j)*HWPX;
                    o[j] = (short)f2bf(p[i00]*w00 + p[i01]*w01 + p[i10]*w10 + p[i11]*w11);
                }
            }
        }
    }
    *(short8*)dst = o;
}

// ---------------------------------------------------------------------------
// t_pad: fp32 channel-major -> padded token-major bf16 (+ zero borders).
// COFF: column offset in output pitch (for concat). Border zeroes cols [0,PITCH).
// block (64,4), grid (73, CI/32, imgs)
__global__ void t_pad(const float* __restrict__ in, unsigned short* __restrict__ outb,
                      int CI, int PITCH, int COFF)
{
    int ppx = blockIdx.x*64 + threadIdx.x;
    if (ppx >= PPXN) return;
    int img = blockIdx.z;
    int c8 = (blockIdx.y*4 + threadIdx.y)*8;
    unsigned short* dst = outb + ((size_t)img*PPXN + ppx)*PITCH;
    int py = ppx/68, pxc = ppx - py*68;
    if (py < 2 || py >= 66 || pxc < 2 || pxc >= 66) {
        short8 z = {};
        *(short8*)(dst + c8) = z;
        if (COFF) *(short8*)(dst + COFF + c8) = z;
        return;
    }
    int pix = ((py-2)<<6) + (pxc-2);
    short8 o;
    #pragma unroll
    for (int j = 0; j < 8; ++j)
        o[j] = (short)f2bf(in[((size_t)img*CI + c8 + j)*HWPX + pix]);
    *(short8*)(dst + COFF + c8) = o;
}

// t_zb: zero the borders of a padded token-major bf16 buffer.
__global__ __launch_bounds__(256) void t_zb(unsigned short* __restrict__ buf, int PITCH) {
    int id = blockIdx.x*256 + threadIdx.x;
    int perpx = PITCH >> 3;
    int ppx = id / perpx, c8 = (id - ppx*perpx) * 8;
    if (ppx >= PPXN) return;
    int py = ppx/68, pxc = ppx - py*68;
    if (py >= 2 && py < 66 && pxc >= 2 && pxc < 66) return;
    short8 z = {};
    *(short8*)(buf + ((size_t)blockIdx.y*PPXN + ppx)*PITCH + c8) = z;
}

// ---------------------------------------------------------------------------
// t_wT: conv weights w[CO][CI][3][3] fp32 -> wT[cotile][kblk][tap][cig][co][8] bf16
// grid (cotiles, NKB), 256 threads; each block emits one 36,864 B chunk.
__global__ __launch_bounds__(256) void t_wT(const float* __restrict__ w,
                                            unsigned short* __restrict__ wT,
                                            int CI, int NKB) {
    int cotile = blockIdx.x, kblk = blockIdx.y;
    int tid = threadIdx.x & 255;
    unsigned short* dst = wT + ((size_t)(cotile*NKB + kblk))*18432;
    #pragma unroll
    for (int it = 0; it < 9; ++it) {
        int idx = it*256 + tid;
        int tap = idx >> 8, sub = idx & 255;
        int cg = sub >> 6, co = sub & 63;
        int cog = cotile*64 + co;
        int ci0 = kblk*32 + cg*8;
        short8 v;
        #pragma unroll
        for (int j = 0; j < 8; ++j) {
            int ci = ci0 + j;
            v[j] = (ci < CI) ? (short)f2bf(w[((size_t)cog*CI + ci)*9 + tap]) : (short)0;
        }
        *(short8*)(dst + (size_t)idx*8) = v;
    }
}

// t_wg: GEMM weights (K=192) -> wg[cotile][kblk6][cig4][co64][8] bf16, optional 2-src
__global__ __launch_bounds__(256) void t_wg(const float* __restrict__ w1,
                                            const float* __restrict__ w2,
                                            unsigned short* __restrict__ wg,
                                            int co_split, int CO) {
    int cotile = blockIdx.x;
    int tid = threadIdx.x & 255;
    unsigned short* dst = wg + (size_t)cotile*12288;
    #pragma unroll
    for (int it = 0; it < 6; ++it) {
        int idx = it*256 + tid;
        int kblk = idx >> 8, sub = idx & 255;
        int cg = sub >> 6, co = sub & 63;
        int cog = cotile*64 + co;
        int ci0 = kblk*32 + cg*8;
        short8 v = {};
        if (cog < CO) {
            const float* row = (cog < co_split) ? w1 + (size_t)cog*192
                                                : w2 + (size_t)(cog - co_split)*192;
            #pragma unroll
            for (int j = 0; j < 8; ++j) v[j] = (short)f2bf(row[ci0 + j]);
        }
        *(short8*)(dst + (size_t)idx*8) = v;
    }
}

// ---------------------------------------------------------------------------
// k_conv: MFMA implicit-GEMM 3x3 conv over padded token-major bf16 input.
// Block 256 thr / 4 waves; tile 64co x (4 rows x 64 px); wave w = row w; mb=4, nb=4.
// x: single-buffered LDS (reg-held prefetch, 2 barriers); w: double-buffered gload_lds.
// OMODE: 0 = bf16 tok unpadded out (leaky)      [Q_tok / V_tok]
//        1 = fp32 ch out + frame-res AND bf16 padded tok cols0-191 of 384-pitch
//        2 = bf16 padded tok out (leaky)        [P_mid]
//        3 = fp32 ch out + res                  [d_out]
template<int DIL, int OMODE>
__global__ __launch_bounds__(256) void k_conv(
    const unsigned short* __restrict__ P, int CIP, int NKB,
    const unsigned short* __restrict__ wT,
    const float* __restrict__ bias, const float* __restrict__ res,
    float* __restrict__ outF, unsigned short* __restrict__ outB, int CO)
{
    constexpr int RR  = 4 + 2*DIL;
    constexpr int XP  = 64 + 2*DIL;
    constexpr int NCH = RR*XP*4;               // 16B chunks in x-tile
    constexpr int NXS = (NCH + 255)/256;
    __shared__ unsigned short s_x[RR*XP*40];   // 80B per px (32ci + pad)
    __shared__ unsigned short s_w[2][18432];   // 9 tap x 4 cig x 64 co x 8ci, dbuf
    int tid = threadIdx.x & 255;
    int cotile = blockIdx.x, ytile = blockIdx.y, img = blockIdx.z;
    int y0 = ytile*4;
    const unsigned short* Pi = P + (size_t)img*PPXN*CIP;
    int w = tid >> 6, lane = tid & 63, lm = lane & 15, cig = lane >> 4;

    short8 xr[NXS];
    // prologue: stage x(0), w(0)
    {
        int k0 = 0;
        #pragma unroll
        for (int it = 0; it < NXS; ++it) {
            int li = it*256 + tid;
            if (li < NCH) {
                int r = li / (XP*4), rem = li - r*(XP*4);
                int col = rem >> 2, cg = rem & 3;
                xr[it] = *(const short8*)(Pi +
                    ((size_t)((y0 + r + 2 - DIL)*68 + col + (2-DIL)))*CIP + k0 + cg*8);
            }
        }
        const unsigned short* ws = wT + ((size_t)cotile*NKB)*18432;
        #pragma unroll
        for (int it = 0; it < 9; ++it)
            gl_lds16(ws + (size_t)(it*256+tid)*8, &s_w[0][(it*256+tid)*8]);
        #pragma unroll
        for (int it = 0; it < NXS; ++it) {
            int li = it*256 + tid;
            if (li < NCH) {
                int r = li / (XP*4), rem = li - r*(XP*4);
                int col = rem >> 2, cg = rem & 3;
                *(short8*)&s_x[(r*XP + col)*40 + cg*8] = xr[it];
            }
        }
    }
    __syncthreads();

    f32x4 acc[4][4] = {};
    int wb = 0;
    for (int kb = 0; kb < NKB; ++kb) {
        bool pf = (kb + 1 < NKB);
        if (pf) {
            int k0 = (kb+1)*32;
            #pragma unroll
            for (int it = 0; it < NXS; ++it) {
                int li = it*256 + tid;
                if (li < NCH) {
                    int r = li / (XP*4), rem = li - r*(XP*4);
                    int col = rem >> 2, cg = rem & 3;
                    xr[it] = *(const short8*)(Pi +
                        ((size_t)((y0 + r + 2 - DIL)*68 + col + (2-DIL)))*CIP + k0 + cg*8);
                }
            }
            const unsigned short* ws = wT + ((size_t)(cotile*NKB + kb + 1))*18432;
            #pragma unroll
            for (int it = 0; it < 9; ++it)
                gl_lds16(ws + (size_t)(it*256+tid)*8, &s_w[wb^1][(it*256+tid)*8]);
        }
        // compute current K-step
        #pragma unroll
        for (int t = 0; t < 9; ++t) {
            int ky = t/3, kx = t - ky*3;
            short8 A[4], Bf[4];
            #pragma unroll
            for (int nb = 0; nb < 4; ++nb)
                Bf[nb] = *(const short8*)&s_x[((w + ky*DIL)*XP + nb*16 + lm + kx*DIL)*40 + cig*8];
            #pragma unroll
            for (int mb = 0; mb < 4; ++mb)
                A[mb] = *(const short8*)&s_w[wb][((t*4 + cig)*64 + mb*16 + lm)*8];
            #pragma unroll
            for (int mb = 0; mb < 4; ++mb)
                #pragma unroll
                for (int nb = 0; nb < 4; ++nb)
                    acc[mb][nb] = __builtin_amdgcn_mfma_f32_16x16x32_bf16(
                        A[mb], Bf[nb], acc[mb][nb], 0, 0, 0);
        }
        __syncthreads();                 // all waves done reading s_x
        if (pf) {
            #pragma unroll
            for (int it = 0; it < NXS; ++it) {
                int li = it*256 + tid;
                if (li < NCH) {
                    int r = li / (XP*4), rem = li - r*(XP*4);
                    int col = rem >> 2, cg = rem & 3;
                    *(short8*)&s_x[(r*XP + col)*40 + cg*8] = xr[it];
                }
            }
        }
        __syncthreads();                 // new x + new w visible
        wb ^= 1;
    }

    // epilogue: D row = co (mb*16 + cig*4 + r), col = px (nb*16 + lm)
    int y = y0 + w;
    #pragma unroll
    for (int mb = 0; mb < 4; ++mb) {
        int cob = cotile*64 + mb*16 + cig*4;
        #pragma unroll
        for (int nb = 0; nb < 4; ++nb) {
            int x = nb*16 + lm;
            int px = (y<<6) + x;
            float vv[4];
            #pragma unroll
            for (int r = 0; r < 4; ++r) {
                float v = acc[mb][nb][r] + bias[cob + r];
                if (OMODE == 0 || OMODE == 2) v = v >= 0.f ? v : 0.1f*v;
                if (OMODE == 1 || OMODE == 3)
                    v += res[((size_t)img*192 + cob + r)*HWPX + px];
                vv[r] = v;
            }
            if (OMODE == 0) {
                int it = cob/192, cc = cob - it*192;
                short4v s;
                #pragma unroll
                for (int r = 0; r < 4; ++r) s[r] = (short)f2bf(vv[r]);
                *(short4v*)(outB + (((size_t)(img*5 + it)*HWPX + px)*192 + cc)) = s;
            } else if (OMODE == 1) {
                #pragma unroll
                for (int r = 0; r < 4; ++r)
                    outF[((size_t)img*192 + cob + r)*HWPX + px] = vv[r];
                int ppx = ((px>>6)+2)*68 + (px&63) + 2;
                short4v s;
                #pragma unroll
                for (int r = 0; r < 4; ++r) s[r] = (short)f2bf(vv[r]);
                *(short4v*)(outB + ((size_t)img*PPXN + ppx)*384 + cob) = s;
            } else if (OMODE == 2) {
                int ppx = ((px>>6)+2)*68 + (px&63) + 2;
                short4v s;
                #pragma unroll
                for (int r = 0; r < 4; ++r) s[r] = (short)f2bf(vv[r]);
                *(short4v*)(outB + ((size_t)img*PPXN + ppx)*192 + cob) = s;
            } else {
                #pragma unroll
                for (int r = 0; r < 4; ++r)
                    outF[((size_t)img*192 + cob + r)*HWPX + px] = vv[r];
            }
        }
    }
}

// ---------------------------------------------------------------------------
// k_gemmm: bf16 MFMA GEMM, K=192. X: [img][4096][192] tok bf16. Tile 64co x 256px.
// GMODE 0: vproj -> vp bf16 [img][4][4096][48]
// GMODE 1: off/attn -> offs fp32 [b][160][LQ], aw fp32 [b][80][LQ]   (CO=240 pad 256)
// GMODE 2: outproj -> P_ff bf16 padded [img][4624][192]
template<int GMODE>
__global__ __launch_bounds__(256) void k_gemmm(
    const unsigned short* __restrict__ X, const unsigned short* __restrict__ WG,
    const float* __restrict__ b1, const float* __restrict__ b2,
    float* __restrict__ o1, float* __restrict__ o2, unsigned short* __restrict__ ob)
{
    __shared__ unsigned short s_x[2][10240];   // 256 px * 40
    __shared__ unsigned short s_w[12288];      // 6 kblk * 4 cig * 64 co * 8
    int tid = threadIdx.x & 255;
    int cotile = blockIdx.x, pxt = blockIdx.y, img = blockIdx.z;
    int px0 = pxt*256;
    const unsigned short* Xi = X + (size_t)img*HWPX*192;
    #pragma unroll
    for (int it = 0; it < 6; ++it)
        gl_lds16(WG + (size_t)cotile*12288 + (it*256+tid)*8, &s_w[(it*256+tid)*8]);
    short8 xr[4];
    #pragma unroll
    for (int it = 0; it < 4; ++it) {
        int li = it*256 + tid;
        xr[it] = *(const short8*)(Xi + (size_t)(px0 + (li>>2))*192 + (li&3)*8);
    }
    #pragma unroll
    for (int it = 0; it < 4; ++it) {
        int li = it*256 + tid;
        *(short8*)&s_x[0][(li>>2)*40 + (li&3)*8] = xr[it];
    }
    __syncthreads();
    int w = tid >> 6, lane = tid & 63, lm = lane & 15, cig = lane >> 4;
    f32x4 acc[4][4] = {};
    int xb = 0;
    for (int kb = 0; kb < 6; ++kb) {
        bool pf = (kb < 5);
        if (pf) {
            int k0 = (kb+1)*32;
            #pragma unroll
            for (int it = 0; it < 4; ++it) {
                int li = it*256 + tid;
                xr[it] = *(const short8*)(Xi + (size_t)(px0 + (li>>2))*192 + k0 + (li&3)*8);
            }
        }
        short8 A[4], Bf[4];
        #pragma unroll
        for (int nb = 0; nb < 4; ++nb)
            Bf[nb] = *(const short8*)&s_x[xb][(w*64 + nb*16 + lm)*40 + cig*8];
        #pragma unroll
        for (int mb = 0; mb < 4; ++mb)
            A[mb] = *(const short8*)&s_w[((kb*4 + cig)*64 + mb*16 + lm)*8];
        #pragma unroll
        for (int mb = 0; mb < 4; ++mb)
            #pragma unroll
            for (int nb = 0; nb < 4; ++nb)
                acc[mb][nb] = __builtin_amdgcn_mfma_f32_16x16x32_bf16(
                    A[mb], Bf[nb], acc[mb][nb], 0, 0, 0);
        if (pf) {
            #pragma unroll
            for (int it = 0; it < 4; ++it) {
                int li = it*256 + tid;
                *(short8*)&s_x[xb^1][(li>>2)*40 + (li&3)*8] = xr[it];
            }
        }
        __syncthreads();
        xb ^= 1;
    }
    int b = img/5, t = img - b*5;
    #pragma unroll
    for (int mb = 0; mb < 4; ++mb) {
        int cob = cotile*64 + mb*16 + cig*4;
        if (GMODE == 1 && cob >= 240) continue;
        #pragma unroll
        for (int nb = 0; nb < 4; ++nb) {
            int px = px0 + w*64 + nb*16 + lm;
            float vv[4];
            #pragma unroll
            for (int r = 0; r < 4; ++r) {
                float bv;
                if (GMODE == 1) bv = (cob + r < 160) ? b1[cob+r] : b2[cob+r-160];
                else bv = b1[cob + r];
                vv[r] = acc[mb][nb][r] + bv;
            }
            if (GMODE == 0) {
                int h = cob/48, d = cob - h*48;
                short4v s;
                #pragma unroll
                for (int r = 0; r < 4; ++r) s[r] = (short)f2bf(vv[r]);
                *(short4v*)(ob + (((size_t)img*4 + h)*HWPX + px)*48 + d) = s;
            } else if (GMODE == 1) {
                #pragma unroll
                for (int r = 0; r < 4; ++r) {
                    int co = cob + r;
                    if (co < 160) o1[((size_t)b*160 + co)*LQ + t*HWPX + px] = vv[r];
                    else          o2[((size_t)b*80 + co-160)*LQ + t*HWPX + px] = vv[r];
                }
            } else {
                int ppx = ((px>>6)+2)*68 + (px&63) + 2;
                short4v s;
                #pragma unroll
                for (int r = 0; r < 4; ++r) s[r] = (short)f2bf(vv[r]);
                *(short4v*)(ob + ((size_t)img*PPXN + ppx)*192 + cob) = s;
            }
        }
    }
}

// ---------------------------------------------------------------------------
// K7: softmax over 20 values at stride LQ (aw: (B, 4*20, LQ))
__global__ __launch_bounds__(256) void k_softmax20(float* __restrict__ aw) {
    int i = blockIdx.x*256 + threadIdx.x;
    int lq = i % LQ;
    int bh = i / LQ;
    float* p = aw + (size_t)bh*20*LQ + lq;
    float e[20];
    float m = -1e30f;
    #pragma unroll
    for (int j = 0; j < 20; ++j) { e[j] = p[(size_t)j*LQ]; m = fmaxf(m, e[j]); }
    float s = 0.f;
    #pragma unroll
    for (int j = 0; j < 20; ++j) { e[j] = expf(e[j]-m); s += e[j]; }
    float inv = 1.f/s;
    #pragma unroll
    for (int j = 0; j < 20; ++j) p[(size_t)j*LQ] = e[j]*inv;
}

// ---------------------------------------------------------------------------
// K8: deformable sampling. vp bf16 [b][l][h][4096][48]; out acc_tok bf16 [b][LQ][192]
__device__ __forceinline__ void addtap(float* acc, const unsigned short* __restrict__ src, float w) {
    const short8* s8 = (const short8*)src;
    #pragma unroll
    for (int q = 0; q < 6; ++q) {
        short8 v = s8[q];
        #pragma unroll
        for (int j = 0; j < 8; ++j)
            acc[q*8+j] += w * bf2f((unsigned short)v[j]);
    }
}

__global__ __launch_bounds__(256) void k_sample(
    const unsigned short* __restrict__ vp, const float* __restrict__ offs,
    const float* __restrict__ aw, const float* __restrict__ flows,
    unsigned short* __restrict__ accout)
{
    int blk = blockIdx.x;
    int b = blk / 320, sub = blk - b*320;
    int h = threadIdx.x >> 6;
    int lq = sub*64 + (threadIdx.x & 63);
    int pix = lq & 4095;
    int x = pix & 63, y = pix >> 6;
    const float* offp = offs + ((size_t)b*160 + h*40)*LQ + lq;
    const float* awp  = aw   + ((size_t)b*80  + h*20)*LQ + lq;
    float acc[48];
    #pragma unroll
    for (int d = 0; d < 48; ++d) acc[d] = 0.f;

    for (int l = 0; l < 5; ++l) {
        float fx = flows[((size_t)(b*5+l)*2+0)*HWPX + pix];
        float fy = flows[((size_t)(b*5+l)*2+1)*HWPX + pix];
        const unsigned short* vpl = vp + ((size_t)(b*5+l)*4 + h)*HWPX*48;
        #pragma unroll
        for (int p = 0; p < 4; ++p) {
            int o = l*4 + p;
            float ox = offp[(size_t)(2*o)*LQ];
            float oy = offp[(size_t)(2*o+1)*LQ];
            float wv = awp[(size_t)o*LQ];
            float sx = (float)x + ox + fx;
            float sy = (float)y + oy + fy;
            float x0f = floorf(sx), y0f = floorf(sy);
            float wx = sx - x0f, wy = sy - y0f;
            int ix0 = (int)x0f, iy0 = (int)y0f;
            float w00 = wv*(1.f-wx)*(1.f-wy), w01 = wv*wx*(1.f-wy);
            float w10 = wv*(1.f-wx)*wy,       w11 = wv*wx*wy;
            bool vx0 = (ix0 >= 0)  && (ix0 <= 63);
            bool vx1 = (ix0 >= -1) && (ix0 <= 62);
            bool vy0 = (iy0 >= 0)  && (iy0 <= 63);
            bool vy1 = (iy0 >= -1) && (iy0 <= 62);
            if (vy0 && vx0) addtap(acc, vpl + (size_t)(iy0*64 + ix0)*48,       w00);
            if (vy0 && vx1) addtap(acc, vpl + (size_t)(iy0*64 + ix0 + 1)*48,   w01);
            if (vy1 && vx0) addtap(acc, vpl + (size_t)((iy0+1)*64 + ix0)*48,   w10);
            if (vy1 && vx1) addtap(acc, vpl + (size_t)((iy0+1)*64 + ix0+1)*48, w11);
        }
    }
    unsigned short* dst = accout + ((size_t)b*LQ + lq)*192 + h*48;
    #pragma unroll
    for (int q = 0; q < 6; ++q) {
        short8 s;
        #pragma unroll
        for (int j = 0; j < 8; ++j) s[j] = (short)f2bf(acc[q*8+j]);
        *(short8*)(dst + q*8) = s;
    }
}

// ---------------------------------------------------------------------------

extern "C" void kernel_launch(void* const* d_in, const int* in_sizes, int n_in,
                              void* d_out, int out_size, void* d_ws, size_t ws_size,
                              hipStream_t stream) {
    (void)in_sizes; (void)n_in; (void)out_size; (void)ws_size;
    const float* frame    = (const float*)d_in[0];
    const float* srcframe = (const float*)d_in[1];
    const float* flow_f   = (const float*)d_in[2];
    const float* flow_b   = (const float*)d_in[3];
    const float* w_qk  = (const float*)d_in[4];  const float* b_qk  = (const float*)d_in[5];
    const float* w_v   = (const float*)d_in[6];  const float* b_v   = (const float*)d_in[7];
    const float* w_vp  = (const float*)d_in[8];  const float* b_vp  = (const float*)d_in[9];
    const float* w_off = (const float*)d_in[10]; const float* b_off = (const float*)d_in[11];
    const float* w_at  = (const float*)d_in[12]; const float* b_at  = (const float*)d_in[13];
    const float* w_out = (const float*)d_in[14]; const float* b_out = (const float*)d_in[15];
    const float* w_ff  = (const float*)d_in[16]; const float* b_ff  = (const float*)d_in[17];
    const float* w_f1  = (const float*)d_in[18]; const float* b_f1  = (const float*)d_in[19];
    const float* w_f2  = (const float*)d_in[20]; const float* b_f2  = (const float*)d_in[21];
    float* out = (float*)d_out;
    char* W = (char*)d_ws;

    // ---- workspace layout (bytes), total 192,182,272 <= ws_size ----
    float*          flows  = (float*)(W + 0);                    // 327,680
    unsigned short* wT_qk  = (unsigned short*)(W + 327680);      // 17,141,760
    unsigned short* wT_v   = (unsigned short*)(W + 17469440);    // 16,588,800
    // after conv_qk completes, the wT_qk slot is recycled for small transforms:
    unsigned short* wT_ff  = (unsigned short*)(W + 327680);      //   663,552
    unsigned short* wT_f1  = (unsigned short*)(W + 991232);      // 1,327,104
    unsigned short* wT_f2  = (unsigned short*)(W + 2318336);     //   663,552
    unsigned short* wg_vp  = (unsigned short*)(W + 2981888);     //    73,728
    unsigned short* wg_oa  = (unsigned short*)(W + 3055616);     //    98,304
    unsigned short* wg_out = (unsigned short*)(W + 3153920);     //    73,728
    unsigned short* P_qk   = (unsigned short*)(W + 34058240);    // 18,348,032
    unsigned short* P_ff   = P_qk;                               // 17,756,160 (reuse)
    unsigned short* P_v    = (unsigned short*)(W + 52406272);    // 17,756,160
    unsigned short* P_mid  = P_v;                                // reuse
    unsigned short* Q_tok  = (unsigned short*)(W + 70162432);    // 15,728,640
    unsigned short* acc_tok= Q_tok;                              // reuse
    unsigned short* V_tok  = (unsigned short*)(W + 85891072);    // 15,728,640
    unsigned short* P_ffn1 = V_tok;                              // 35,512,320 (V_tok+vp+pad)
    unsigned short* vp     = (unsigned short*)(W + 101619712);   // 15,728,640 (+4,055,040 pad)
    float*          offs   = (float*)(W + 121403392);            // 26,214,400
    float*          aw     = (float*)(W + 147617792);            // 13,107,200
    float*          out1   = (float*)(W + 160724992);            // 31,457,280

    dim3 bp(64, 4);

    // 1. flow composition
    k_flow<<<32, 256, 0, stream>>>(flow_f, flow_b, flows);
    // 2. big conv weight transforms
    t_wT<<<dim3(15,31), 256, 0, stream>>>(w_qk, wT_qk, 976, 31);
    t_wT<<<dim3(15,30), 256, 0, stream>>>(w_v,  wT_v,  960, 30);
    // 3. fused qk_in assembly (warp + pad + bf16)
    k_qkin<<<dim3(73,31,2), bp, 0, stream>>>(frame, flow_f, flow_b, flows, P_qk);
    // 4. frame -> padded tok bf16 (conv_v input)
    t_pad<<<dim3(73,30,2), bp, 0, stream>>>(frame, P_v, 960, 960, 0);
    // 5. conv_qk -> Q_tok (leaky)
    k_conv<1,0><<<dim3(15,16,2), 256, 0, stream>>>(P_qk, 992, 31, wT_qk, b_qk, nullptr,
                                                   nullptr, Q_tok, 960);
    // 6. conv_v -> V_tok (leaky)
    k_conv<1,0><<<dim3(15,16,2), 256, 0, stream>>>(P_v, 960, 30, wT_v, b_v, nullptr,
                                                   nullptr, V_tok, 960);
    // 7. small transforms (recycle wT_qk slot — safe after step 5)
    t_wT<<<dim3(3,6),  256, 0, stream>>>(w_ff, wT_ff, 192, 6);
    t_wT<<<dim3(3,12), 256, 0, stream>>>(w_f1, wT_f1, 384, 12);
    t_wT<<<dim3(3,6),  256, 0, stream>>>(w_f2, wT_f2, 192, 6);
    t_wg<<<3, 256, 0, stream>>>(w_vp,  nullptr, wg_vp, 192, 192);
    t_wg<<<4, 256, 0, stream>>>(w_off, w_at,    wg_oa, 160, 240);
    t_wg<<<3, 256, 0, stream>>>(w_out, nullptr, wg_out, 192, 192);
    // 8. zero borders of padded buffers built by epilogues
    t_zb<<<dim3(434,10), 256, 0, stream>>>(P_ff, 192);
    t_zb<<<dim3(434,10), 256, 0, stream>>>(P_mid, 192);
    // 9. v_proj GEMM -> vp bf16
    k_gemmm<0><<<dim3(3,16,10), 256, 0, stream>>>(V_tok, wg_vp, b_vp, nullptr,
                                                  nullptr, nullptr, vp);
    // 10. offsets + attn logits GEMM
    k_gemmm<1><<<dim3(4,16,10), 256, 0, stream>>>(Q_tok, wg_oa, b_off, b_at,
                                                  offs, aw, nullptr);
    // 11. softmax over 20
    k_softmax20<<<640, 256, 0, stream>>>(aw);
    // 12. deformable sampling -> acc_tok bf16
    k_sample<<<640, 256, 0, stream>>>(vp, offs, aw, flows, acc_tok);
    // 13. srcframe -> P_ffn1 cols 192..383 + all borders (after vp/V_tok dead)
    t_pad<<<dim3(73,6,10), bp, 0, stream>>>(srcframe, P_ffn1, 192, 384, 192);
    // 14. output projection -> P_ff (padded tok bf16 interior)
    k_gemmm<2><<<dim3(3,16,10), 256, 0, stream>>>(acc_tok, wg_out, b_out, nullptr,
                                                  nullptr, nullptr, P_ff);
    // 15. conv_ff + frame residual -> out1 fp32 AND P_ffn1 cols 0..191
    k_conv<1,1><<<dim3(3,16,10), 256, 0, stream>>>(P_ff, 192, 6, wT_ff, b_ff, frame,
                                                   out1, P_ffn1, 192);
    // 16. ffn1 (dilation 2, leaky) -> P_mid
    k_conv<2,2><<<dim3(3,16,10), 256, 0, stream>>>(P_ffn1, 384, 12, wT_f1, b_f1, nullptr,
                                                   nullptr, P_mid, 192);
    // 17. ffn2 + out1 residual -> d_out
    k_conv<1,3><<<dim3(3,16,10), 256, 0, stream>>>(P_mid, 192, 6, wT_f2, b_f2, out1,
                                                   out, nullptr, 192);
    // 18. second output = srcframe passthrough
    hipMemcpyAsync(out + (size_t)2*5*192*HWPX, srcframe,
                   (size_t)2*5*192*HWPX*sizeof(float),
                   hipMemcpyDeviceToDevice, stream);
}

// Round 4
// 894.555 us; speedup vs baseline: 18.4616x; 1.1310x over previous
//
#include <hip/hip_runtime.h>

// ---------------------------------------------------------------------------
// DeformableAttnBlock — round 4: conflict-free LDS planes + 2 blocks/CU convs.
// B=2, T=5, C=192, H=W=64, NH=4, NL=5, NP=4, DH=48
// Padded images: 68x68 (pad=2), token-major bf16, channel-count mult of 32.
// ---------------------------------------------------------------------------

#define HWPX 4096
#define PPXN 4624      // 68*68
#define LQ   20480

typedef __attribute__((ext_vector_type(8))) short  short8;
typedef __attribute__((ext_vector_type(4))) short  short4v;
typedef __attribute__((ext_vector_type(4))) float  f32x4;

__device__ __forceinline__ unsigned short f2bf(float f) {
    unsigned u = __float_as_uint(f);
    unsigned r = (u + 0x7FFF + ((u >> 16) & 1)) >> 16;   // RNE
    return (unsigned short)r;
}
__device__ __forceinline__ float bf2f(unsigned short s) {
    return __uint_as_float(((unsigned)s) << 16);
}

__device__ __forceinline__ void gl_lds16(const unsigned short* g, unsigned short* l) {
    __builtin_amdgcn_global_load_lds(
        (const __attribute__((address_space(1))) unsigned int*)g,
        (__attribute__((address_space(3))) unsigned int*)l, 16, 0, 0);
}

// ---------------------------------------------------------------------------
// K1: flow composition. flows layout (B, 5, 2, HW): l0=ff02,l1=ff12,l2=0,l3=fb32,l4=fb42
__device__ __forceinline__ float bsample(const float* __restrict__ p, float sx, float sy) {
    sx = fminf(fmaxf(sx, 0.f), 63.f);
    sy = fminf(fmaxf(sy, 0.f), 63.f);
    float x0 = floorf(sx), y0 = floorf(sy);
    int ix0 = (int)x0, iy0 = (int)y0;
    int ix1 = ix0 < 63 ? ix0 + 1 : 63;
    int iy1 = iy0 < 63 ? iy0 + 1 : 63;
    float wx = sx - x0, wy = sy - y0;
    float v00 = p[iy0*64+ix0], v01 = p[iy0*64+ix1];
    float v10 = p[iy1*64+ix0], v11 = p[iy1*64+ix1];
    return (v00*(1.f-wx) + v01*wx)*(1.f-wy) + (v10*(1.f-wx) + v11*wx)*wy;
}

__global__ __launch_bounds__(256) void k_flow(const float* __restrict__ ff,
                                              const float* __restrict__ fb,
                                              float* __restrict__ flows) {
    int i = blockIdx.x*256 + threadIdx.x;
    int b = i >> 12, pix = i & 4095;
    int x = pix & 63, y = pix >> 6;
    const float* ff01 = ff + (size_t)(b*4+0)*2*HWPX;
    const float* ff12 = ff + (size_t)(b*4+1)*2*HWPX;
    const float* fb32 = fb + (size_t)(b*4+2)*2*HWPX;
    const float* fb43 = fb + (size_t)(b*4+3)*2*HWPX;
    float* F = flows + (size_t)b*5*2*HWPX;
    float ax = ff01[pix], ay = ff01[HWPX+pix];
    float sx = bsample(ff12,      (float)x+ax, (float)y+ay);
    float sy = bsample(ff12+HWPX, (float)x+ax, (float)y+ay);
    F[0*2*HWPX + pix]        = ax + sx;
    F[0*2*HWPX + HWPX + pix] = ay + sy;
    F[1*2*HWPX + pix]        = ff12[pix];
    F[1*2*HWPX + HWPX + pix] = ff12[HWPX+pix];
    F[2*2*HWPX + pix]        = 0.f;
    F[2*2*HWPX + HWPX + pix] = 0.f;
    F[3*2*HWPX + pix]        = fb32[pix];
    F[3*2*HWPX + HWPX + pix] = fb32[HWPX+pix];
    float bx = fb43[pix], by = fb43[HWPX+pix];
    float tx = bsample(fb32,      (float)x+bx, (float)y+by);
    float ty = bsample(fb32+HWPX, (float)x+bx, (float)y+by);
    F[4*2*HWPX + pix]        = bx + tx;
    F[4*2*HWPX + HWPX + pix] = by + ty;
}

// ---------------------------------------------------------------------------
// K2: fused qk_in assembly: warp + pad + bf16 pack -> P_qk [b][4624][992]
__global__ void k_qkin(const float* __restrict__ frame, const float* __restrict__ ff,
                       const float* __restrict__ fb, const float* __restrict__ flows,
                       unsigned short* __restrict__ Pqk)
{
    int ppx = blockIdx.x*64 + threadIdx.x;
    if (ppx >= PPXN) return;
    int b = blockIdx.z;
    int c8 = (blockIdx.y*4 + threadIdx.y)*8;
    unsigned short* dst = Pqk + ((size_t)b*PPXN + ppx)*992 + c8;
    int py = ppx/68, pxc = ppx - py*68;
    short8 o = {};
    if (py >= 2 && py < 66 && pxc >= 2 && pxc < 66 && c8 < 976) {
        int y = py-2, x = pxc-2, pix = (y<<6)+x;
        if (c8 >= 960) {
            #pragma unroll
            for (int j = 0; j < 8; ++j) {
                int k = c8 - 960 + j;
                float v = (k < 8) ? ff[((size_t)b*8 + k)*HWPX + pix]
                                  : fb[((size_t)b*8 + k - 8)*HWPX + pix];
                o[j] = (short)f2bf(v);
            }
        } else {
            int slot = c8/192, cc = c8 - slot*192;
            const float* base = frame + ((size_t)(b*5 + slot)*192)*HWPX;
            if (slot == 2) {
                #pragma unroll
                for (int j = 0; j < 8; ++j)
                    o[j] = (short)f2bf(base[(size_t)(cc+j)*HWPX + pix]);
            } else {
                const float* F = flows + ((size_t)(b*5 + slot)*2)*HWPX;
                float sx = fminf(fmaxf((float)x + F[pix], 0.f), 63.f);
                float sy = fminf(fmaxf((float)y + F[HWPX + pix], 0.f), 63.f);
                float x0 = floorf(sx), y0 = floorf(sy);
                int ix0 = (int)x0, iy0 = (int)y0;
                int ix1 = ix0 < 63 ? ix0+1 : 63, iy1 = iy0 < 63 ? iy0+1 : 63;
                float wx = sx - x0, wy = sy - y0;
                float w00 = (1.f-wx)*(1.f-wy), w01 = wx*(1.f-wy);
                float w10 = (1.f-wx)*wy,       w11 = wx*wy;
                int i00 = iy0*64+ix0, i01 = iy0*64+ix1;
                int i10 = iy1*64+ix0, i11 = iy1*64+ix1;
                #pragma unroll
                for (int j = 0; j < 8; ++j) {
                    const float* p = base + (size_t)(cc+j)*HWPX;
                    o[j] = (short)f2bf(p[i00]*w00 + p[i01]*w01 + p[i10]*w10 + p[i11]*w11);
                }
            }
        }
    }
    *(short8*)dst = o;
}

// ---------------------------------------------------------------------------
// t_pad: fp32 channel-major -> padded token-major bf16 (+ zero borders).
__global__ void t_pad(const float* __restrict__ in, unsigned short* __restrict__ outb,
                      int CI, int PITCH, int COFF)
{
    int ppx = blockIdx.x*64 + threadIdx.x;
    if (ppx >= PPXN) return;
    int img = blockIdx.z;
    int c8 = (blockIdx.y*4 + threadIdx.y)*8;
    unsigned short* dst = outb + ((size_t)img*PPXN + ppx)*PITCH;
    int py = ppx/68, pxc = ppx - py*68;
    if (py < 2 || py >= 66 || pxc < 2 || pxc >= 66) {
        short8 z = {};
        *(short8*)(dst + c8) = z;
        if (COFF) *(short8*)(dst + COFF + c8) = z;
        return;
    }
    int pix = ((py-2)<<6) + (pxc-2);
    short8 o;
    #pragma unroll
    for (int j = 0; j < 8; ++j)
        o[j] = (short)f2bf(in[((size_t)img*CI + c8 + j)*HWPX + pix]);
    *(short8*)(dst + COFF + c8) = o;
}

// t_zb: zero the borders of a padded token-major bf16 buffer.
__global__ __launch_bounds__(256) void t_zb(unsigned short* __restrict__ buf, int PITCH) {
    int id = blockIdx.x*256 + threadIdx.x;
    int perpx = PITCH >> 3;
    int ppx = id / perpx, c8 = (id - ppx*perpx) * 8;
    if (ppx >= PPXN) return;
    int py = ppx/68, pxc = ppx - py*68;
    if (py >= 2 && py < 66 && pxc >= 2 && pxc < 66) return;
    short8 z = {};
    *(short8*)(buf + ((size_t)blockIdx.y*PPXN + ppx)*PITCH + c8) = z;
}

// ---------------------------------------------------------------------------
// t_wT: conv weights w[CO][CI][3][3] fp32 -> wT[cotile][kblk][tap][cig][co][8] bf16
__global__ __launch_bounds__(256) void t_wT(const float* __restrict__ w,
                                            unsigned short* __restrict__ wT,
                                            int CI, int NKB) {
    int cotile = blockIdx.x, kblk = blockIdx.y;
    int tid = threadIdx.x & 255;
    unsigned short* dst = wT + ((size_t)(cotile*NKB + kblk))*18432;
    #pragma unroll
    for (int it = 0; it < 9; ++it) {
        int idx = it*256 + tid;
        int tap = idx >> 8, sub = idx & 255;
        int cg = sub >> 6, co = sub & 63;
        int cog = cotile*64 + co;
        int ci0 = kblk*32 + cg*8;
        short8 v;
        #pragma unroll
        for (int j = 0; j < 8; ++j) {
            int ci = ci0 + j;
            v[j] = (ci < CI) ? (short)f2bf(w[((size_t)cog*CI + ci)*9 + tap]) : (short)0;
        }
        *(short8*)(dst + (size_t)idx*8) = v;
    }
}

// t_wg: GEMM weights (K=192) -> wg[cotile][kblk6][cig4][co64][8] bf16, optional 2-src
__global__ __launch_bounds__(256) void t_wg(const float* __restrict__ w1,
                                            const float* __restrict__ w2,
                                            unsigned short* __restrict__ wg,
                                            int co_split, int CO) {
    int cotile = blockIdx.x;
    int tid = threadIdx.x & 255;
    unsigned short* dst = wg + (size_t)cotile*12288;
    #pragma unroll
    for (int it = 0; it < 6; ++it) {
        int idx = it*256 + tid;
        int kblk = idx >> 8, sub = idx & 255;
        int cg = sub >> 6, co = sub & 63;
        int cog = cotile*64 + co;
        int ci0 = kblk*32 + cg*8;
        short8 v = {};
        if (cog < CO) {
            const float* row = (cog < co_split) ? w1 + (size_t)cog*192
                                                : w2 + (size_t)(cog - co_split)*192;
            #pragma unroll
            for (int j = 0; j < 8; ++j) v[j] = (short)f2bf(row[ci0 + j]);
        }
        *(short8*)(dst + (size_t)idx*8) = v;
    }
}

// ---------------------------------------------------------------------------
// k_conv: MFMA implicit-GEMM 3x3 conv over padded token-major bf16 input.
// Block 256 thr / 4 waves; tile 64co x (4 rows x 64 px); wave w = row w; mb=4, nb=4.
// LDS: x in 4 ci-planes [cig][row][col][16B] (conflict-free 256B-contiguous reads);
//      w single-buffer restaged per kb via global_load_lds in the barrier gap.
template<int DIL, int OMODE>
__global__ __launch_bounds__(256, 2) void k_conv(
    const unsigned short* __restrict__ P, int CIP, int NKB,
    const unsigned short* __restrict__ wT,
    const float* __restrict__ bias, const float* __restrict__ res,
    float* __restrict__ outF, unsigned short* __restrict__ outB, int CO)
{
    constexpr int RR    = 4 + 2*DIL;
    constexpr int XP    = 64 + 2*DIL;
    constexpr int PLANE = RR*XP*16;            // bytes per ci-plane
    constexpr int NCH   = RR*XP*4;             // 16B chunks in x-tile
    constexpr int NXS   = (NCH + 255)/256;
    __shared__ unsigned char  s_x[4*PLANE];    // DIL1: 25,344 B  DIL2: 34,816 B
    __shared__ unsigned short s_w[18432];      // 36,864 B (single buffer)
    int tid = threadIdx.x & 255;
    int cotile = blockIdx.x, ytile = blockIdx.y, img = blockIdx.z;
    int y0 = ytile*4;
    const unsigned short* Pi = P + (size_t)img*PPXN*CIP;
    int w = tid >> 6, lane = tid & 63, lm = lane & 15, cig = lane >> 4;

    short8 xr[NXS];
    // prologue: load x(0) regs, stage w(0), write x(0)
    #pragma unroll
    for (int it = 0; it < NXS; ++it) {
        int li = it*256 + tid;
        if (li < NCH) {
            int p = li / (RR*XP), rem = li - p*(RR*XP);
            int r = rem / XP, col = rem - r*XP;
            xr[it] = *(const short8*)(Pi +
                ((size_t)((y0 + r + 2 - DIL)*68 + col + (2-DIL)))*CIP + p*8);
        }
    }
    {
        const unsigned short* ws = wT + ((size_t)cotile*NKB)*18432;
        #pragma unroll
        for (int it = 0; it < 9; ++it)
            gl_lds16(ws + (size_t)(it*256+tid)*8, &s_w[(it*256+tid)*8]);
    }
    #pragma unroll
    for (int it = 0; it < NXS; ++it) {
        int li = it*256 + tid;
        if (li < NCH) {
            int p = li / (RR*XP), rem = li - p*(RR*XP);
            *(short8*)&s_x[p*PLANE + rem*16] = xr[it];
        }
    }
    __syncthreads();

    f32x4 acc[4][4] = {};
    for (int kb = 0; kb < NKB; ++kb) {
        bool pf = (kb + 1 < NKB);
        if (pf) {
            int k0 = (kb+1)*32;
            #pragma unroll
            for (int it = 0; it < NXS; ++it) {
                int li = it*256 + tid;
                if (li < NCH) {
                    int p = li / (RR*XP), rem = li - p*(RR*XP);
                    int r = rem / XP, col = rem - r*XP;
                    xr[it] = *(const short8*)(Pi +
                        ((size_t)((y0 + r + 2 - DIL)*68 + col + (2-DIL)))*CIP + k0 + p*8);
                }
            }
        }
        // compute current K-step
        #pragma unroll
        for (int t = 0; t < 9; ++t) {
            int ky = t/3, kx = t - ky*3;
            short8 A[4], Bf[4];
            #pragma unroll
            for (int nb = 0; nb < 4; ++nb)
                Bf[nb] = *(const short8*)&s_x[cig*PLANE +
                           ((w + ky*DIL)*XP + nb*16 + lm + kx*DIL)*16];
            #pragma unroll
            for (int mb = 0; mb < 4; ++mb)
                A[mb] = *(const short8*)&s_w[((t*4 + cig)*64 + mb*16 + lm)*8];
            #pragma unroll
            for (int mb = 0; mb < 4; ++mb)
                #pragma unroll
                for (int nb = 0; nb < 4; ++nb)
                    acc[mb][nb] = __builtin_amdgcn_mfma_f32_16x16x32_bf16(
                        A[mb], Bf[nb], acc[mb][nb], 0, 0, 0);
        }
        __syncthreads();                 // all waves done reading s_x, s_w
        if (pf) {
            const unsigned short* ws = wT + ((size_t)(cotile*NKB + kb + 1))*18432;
            #pragma unroll
            for (int it = 0; it < 9; ++it)
                gl_lds16(ws + (size_t)(it*256+tid)*8, &s_w[(it*256+tid)*8]);
            #pragma unroll
            for (int it = 0; it < NXS; ++it) {
                int li = it*256 + tid;
                if (li < NCH) {
                    int p = li / (RR*XP), rem = li - p*(RR*XP);
                    *(short8*)&s_x[p*PLANE + rem*16] = xr[it];
                }
            }
        }
        __syncthreads();                 // new x + new w visible (drains vmcnt)
    }

    // epilogue: D row = co (mb*16 + cig*4 + r), col = px (nb*16 + lm)
    int y = y0 + w;
    #pragma unroll
    for (int mb = 0; mb < 4; ++mb) {
        int cob = cotile*64 + mb*16 + cig*4;
        #pragma unroll
        for (int nb = 0; nb < 4; ++nb) {
            int x = nb*16 + lm;
            int px = (y<<6) + x;
            float vv[4];
            #pragma unroll
            for (int r = 0; r < 4; ++r) {
                float v = acc[mb][nb][r] + bias[cob + r];
                if (OMODE == 0 || OMODE == 2) v = v >= 0.f ? v : 0.1f*v;
                if (OMODE == 1 || OMODE == 3)
                    v += res[((size_t)img*192 + cob + r)*HWPX + px];
                vv[r] = v;
            }
            if (OMODE == 0) {
                int it = cob/192, cc = cob - it*192;
                short4v s;
                #pragma unroll
                for (int r = 0; r < 4; ++r) s[r] = (short)f2bf(vv[r]);
                *(short4v*)(outB + (((size_t)(img*5 + it)*HWPX + px)*192 + cc)) = s;
            } else if (OMODE == 1) {
                #pragma unroll
                for (int r = 0; r < 4; ++r)
                    outF[((size_t)img*192 + cob + r)*HWPX + px] = vv[r];
                int ppx = ((px>>6)+2)*68 + (px&63) + 2;
                short4v s;
                #pragma unroll
                for (int r = 0; r < 4; ++r) s[r] = (short)f2bf(vv[r]);
                *(short4v*)(outB + ((size_t)img*PPXN + ppx)*384 + cob) = s;
            } else if (OMODE == 2) {
                int ppx = ((px>>6)+2)*68 + (px&63) + 2;
                short4v s;
                #pragma unroll
                for (int r = 0; r < 4; ++r) s[r] = (short)f2bf(vv[r]);
                *(short4v*)(outB + ((size_t)img*PPXN + ppx)*192 + cob) = s;
            } else {
                #pragma unroll
                for (int r = 0; r < 4; ++r)
                    outF[((size_t)img*192 + cob + r)*HWPX + px] = vv[r];
            }
        }
    }
}

// ---------------------------------------------------------------------------
// k_gemmm: bf16 MFMA GEMM, K=192. X: [img][4096][192] tok bf16. Tile 64co x 256px.
// LDS x in 4 ci-planes [cig][256px][16B], double-buffered; conflict-free reads.
// GMODE 0: vproj -> vp bf16 [img][4][4096][48]
// GMODE 1: off/attn -> offs fp32 [b][160][LQ], aw fp32 [b][80][LQ]
// GMODE 2: outproj -> P_ff bf16 padded [img][4624][192]
template<int GMODE>
__global__ __launch_bounds__(256) void k_gemmm(
    const unsigned short* __restrict__ X, const unsigned short* __restrict__ WG,
    const float* __restrict__ b1, const float* __restrict__ b2,
    float* __restrict__ o1, float* __restrict__ o2, unsigned short* __restrict__ ob)
{
    __shared__ unsigned char  s_x[2][4*4096];  // planes [cig][256px][16B]
    __shared__ unsigned short s_w[12288];
    int tid = threadIdx.x & 255;
    int cotile = blockIdx.x, pxt = blockIdx.y, img = blockIdx.z;
    int px0 = pxt*256;
    const unsigned short* Xi = X + (size_t)img*HWPX*192;
    #pragma unroll
    for (int it = 0; it < 6; ++it)
        gl_lds16(WG + (size_t)cotile*12288 + (it*256+tid)*8, &s_w[(it*256+tid)*8]);
    short8 xr[4];
    #pragma unroll
    for (int it = 0; it < 4; ++it)
        xr[it] = *(const short8*)(Xi + (size_t)(px0 + tid)*192 + it*8);
    #pragma unroll
    for (int it = 0; it < 4; ++it)
        *(short8*)&s_x[0][it*4096 + tid*16] = xr[it];
    __syncthreads();
    int w = tid >> 6, lane = tid & 63, lm = lane & 15, cig = lane >> 4;
    f32x4 acc[4][4] = {};
    int xb = 0;
    for (int kb = 0; kb < 6; ++kb) {
        bool pf = (kb < 5);
        if (pf) {
            int k0 = (kb+1)*32;
            #pragma unroll
            for (int it = 0; it < 4; ++it)
                xr[it] = *(const short8*)(Xi + (size_t)(px0 + tid)*192 + k0 + it*8);
        }
        short8 A[4], Bf[4];
        #pragma unroll
        for (int nb = 0; nb < 4; ++nb)
            Bf[nb] = *(const short8*)&s_x[xb][cig*4096 + (w*64 + nb*16 + lm)*16];
        #pragma unroll
        for (int mb = 0; mb < 4; ++mb)
            A[mb] = *(const short8*)&s_w[((kb*4 + cig)*64 + mb*16 + lm)*8];
        #pragma unroll
        for (int mb = 0; mb < 4; ++mb)
            #pragma unroll
            for (int nb = 0; nb < 4; ++nb)
                acc[mb][nb] = __builtin_amdgcn_mfma_f32_16x16x32_bf16(
                    A[mb], Bf[nb], acc[mb][nb], 0, 0, 0);
        if (pf) {
            #pragma unroll
            for (int it = 0; it < 4; ++it)
                *(short8*)&s_x[xb^1][it*4096 + tid*16] = xr[it];
        }
        __syncthreads();
        xb ^= 1;
    }
    int b = img/5, t = img - b*5;
    #pragma unroll
    for (int mb = 0; mb < 4; ++mb) {
        int cob = cotile*64 + mb*16 + cig*4;
        if (GMODE == 1 && cob >= 240) continue;
        #pragma unroll
        for (int nb = 0; nb < 4; ++nb) {
            int px = px0 + w*64 + nb*16 + lm;
            float vv[4];
            #pragma unroll
            for (int r = 0; r < 4; ++r) {
                float bv;
                if (GMODE == 1) bv = (cob + r < 160) ? b1[cob+r] : b2[cob+r-160];
                else bv = b1[cob + r];
                vv[r] = acc[mb][nb][r] + bv;
            }
            if (GMODE == 0) {
                int h = cob/48, d = cob - h*48;
                short4v s;
                #pragma unroll
                for (int r = 0; r < 4; ++r) s[r] = (short)f2bf(vv[r]);
                *(short4v*)(ob + (((size_t)img*4 + h)*HWPX + px)*48 + d) = s;
            } else if (GMODE == 1) {
                #pragma unroll
                for (int r = 0; r < 4; ++r) {
                    int co = cob + r;
                    if (co < 160) o1[((size_t)b*160 + co)*LQ + t*HWPX + px] = vv[r];
                    else          o2[((size_t)b*80 + co-160)*LQ + t*HWPX + px] = vv[r];
                }
            } else {
                int ppx = ((px>>6)+2)*68 + (px&63) + 2;
                short4v s;
                #pragma unroll
                for (int r = 0; r < 4; ++r) s[r] = (short)f2bf(vv[r]);
                *(short4v*)(ob + ((size_t)img*PPXN + ppx)*192 + cob) = s;
            }
        }
    }
}

// ---------------------------------------------------------------------------
// K7: softmax over 20 values at stride LQ (aw: (B, 4*20, LQ))
__global__ __launch_bounds__(256) void k_softmax20(float* __restrict__ aw) {
    int i = blockIdx.x*256 + threadIdx.x;
    int lq = i % LQ;
    int bh = i / LQ;
    float* p = aw + (size_t)bh*20*LQ + lq;
    float e[20];
    float m = -1e30f;
    #pragma unroll
    for (int j = 0; j < 20; ++j) { e[j] = p[(size_t)j*LQ]; m = fmaxf(m, e[j]); }
    float s = 0.f;
    #pragma unroll
    for (int j = 0; j < 20; ++j) { e[j] = expf(e[j]-m); s += e[j]; }
    float inv = 1.f/s;
    #pragma unroll
    for (int j = 0; j < 20; ++j) p[(size_t)j*LQ] = e[j]*inv;
}

// ---------------------------------------------------------------------------
// K8: deformable sampling. vp bf16 [b][l][h][4096][48]; out acc_tok bf16 [b][LQ][192]
__device__ __forceinline__ void addtap(float* acc, const unsigned short* __restrict__ src, float w) {
    const short8* s8 = (const short8*)src;
    #pragma unroll
    for (int q = 0; q < 6; ++q) {
        short8 v = s8[q];
        #pragma unroll
        for (int j = 0; j < 8; ++j)
            acc[q*8+j] += w * bf2f((unsigned short)v[j]);
    }
}

__global__ __launch_bounds__(256) void k_sample(
    const unsigned short* __restrict__ vp, const float* __restrict__ offs,
    const float* __restrict__ aw, const float* __restrict__ flows,
    unsigned short* __restrict__ accout)
{
    int blk = blockIdx.x;
    int b = blk / 320, sub = blk - b*320;
    int h = threadIdx.x >> 6;
    int lq = sub*64 + (threadIdx.x & 63);
    int pix = lq & 4095;
    int x = pix & 63, y = pix >> 6;
    const float* offp = offs + ((size_t)b*160 + h*40)*LQ + lq;
    const float* awp  = aw   + ((size_t)b*80  + h*20)*LQ + lq;
    float acc[48];
    #pragma unroll
    for (int d = 0; d < 48; ++d) acc[d] = 0.f;

    for (int l = 0; l < 5; ++l) {
        float fx = flows[((size_t)(b*5+l)*2+0)*HWPX + pix];
        float fy = flows[((size_t)(b*5+l)*2+1)*HWPX + pix];
        const unsigned short* vpl = vp + ((size_t)(b*5+l)*4 + h)*HWPX*48;
        #pragma unroll
        for (int p = 0; p < 4; ++p) {
            int o = l*4 + p;
            float ox = offp[(size_t)(2*o)*LQ];
            float oy = offp[(size_t)(2*o+1)*LQ];
            float wv = awp[(size_t)o*LQ];
            float sx = (float)x + ox + fx;
            float sy = (float)y + oy + fy;
            float x0f = floorf(sx), y0f = floorf(sy);
            float wx = sx - x0f, wy = sy - y0f;
            int ix0 = (int)x0f, iy0 = (int)y0f;
            float w00 = wv*(1.f-wx)*(1.f-wy), w01 = wv*wx*(1.f-wy);
            float w10 = wv*(1.f-wx)*wy,       w11 = wv*wx*wy;
            bool vx0 = (ix0 >= 0)  && (ix0 <= 63);
            bool vx1 = (ix0 >= -1) && (ix0 <= 62);
            bool vy0 = (iy0 >= 0)  && (iy0 <= 63);
            bool vy1 = (iy0 >= -1) && (iy0 <= 62);
            if (vy0 && vx0) addtap(acc, vpl + (size_t)(iy0*64 + ix0)*48,       w00);
            if (vy0 && vx1) addtap(acc, vpl + (size_t)(iy0*64 + ix0 + 1)*48,   w01);
            if (vy1 && vx0) addtap(acc, vpl + (size_t)((iy0+1)*64 + ix0)*48,   w10);
            if (vy1 && vx1) addtap(acc, vpl + (size_t)((iy0+1)*64 + ix0+1)*48, w11);
        }
    }
    unsigned short* dst = accout + ((size_t)b*LQ + lq)*192 + h*48;
    #pragma unroll
    for (int q = 0; q < 6; ++q) {
        short8 s;
        #pragma unroll
        for (int j = 0; j < 8; ++j) s[j] = (short)f2bf(acc[q*8+j]);
        *(short8*)(dst + q*8) = s;
    }
}

// ---------------------------------------------------------------------------

extern "C" void kernel_launch(void* const* d_in, const int* in_sizes, int n_in,
                              void* d_out, int out_size, void* d_ws, size_t ws_size,
                              hipStream_t stream) {
    (void)in_sizes; (void)n_in; (void)out_size; (void)ws_size;
    const float* frame    = (const float*)d_in[0];
    const float* srcframe = (const float*)d_in[1];
    const float* flow_f   = (const float*)d_in[2];
    const float* flow_b   = (const float*)d_in[3];
    const float* w_qk  = (const float*)d_in[4];  const float* b_qk  = (const float*)d_in[5];
    const float* w_v   = (const float*)d_in[6];  const float* b_v   = (const float*)d_in[7];
    const float* w_vp  = (const float*)d_in[8];  const float* b_vp  = (const float*)d_in[9];
    const float* w_off = (const float*)d_in[10]; const float* b_off = (const float*)d_in[11];
    const float* w_at  = (const float*)d_in[12]; const float* b_at  = (const float*)d_in[13];
    const float* w_out = (const float*)d_in[14]; const float* b_out = (const float*)d_in[15];
    const float* w_ff  = (const float*)d_in[16]; const float* b_ff  = (const float*)d_in[17];
    const float* w_f1  = (const float*)d_in[18]; const float* b_f1  = (const float*)d_in[19];
    const float* w_f2  = (const float*)d_in[20]; const float* b_f2  = (const float*)d_in[21];
    float* out = (float*)d_out;
    char* W = (char*)d_ws;

    // ---- workspace layout (bytes), total 192,182,272 <= ws_size ----
    float*          flows  = (float*)(W + 0);                    // 327,680
    unsigned short* wT_qk  = (unsigned short*)(W + 327680);      // 17,141,760
    unsigned short* wT_v   = (unsigned short*)(W + 17469440);    // 16,588,800
    unsigned short* wT_ff  = (unsigned short*)(W + 327680);      //   663,552
    unsigned short* wT_f1  = (unsigned short*)(W + 991232);      // 1,327,104
    unsigned short* wT_f2  = (unsigned short*)(W + 2318336);     //   663,552
    unsigned short* wg_vp  = (unsigned short*)(W + 2981888);     //    73,728
    unsigned short* wg_oa  = (unsigned short*)(W + 3055616);     //    98,304
    unsigned short* wg_out = (unsigned short*)(W + 3153920);     //    73,728
    unsigned short* P_qk   = (unsigned short*)(W + 34058240);    // 18,348,032
    unsigned short* P_ff   = P_qk;                               // reuse
    unsigned short* P_v    = (unsigned short*)(W + 52406272);    // 17,756,160
    unsigned short* P_mid  = P_v;                                // reuse
    unsigned short* Q_tok  = (unsigned short*)(W + 70162432);    // 15,728,640
    unsigned short* acc_tok= Q_tok;                              // reuse
    unsigned short* V_tok  = (unsigned short*)(W + 85891072);    // 15,728,640
    unsigned short* P_ffn1 = V_tok;                              // reuse (V_tok+vp+pad)
    unsigned short* vp     = (unsigned short*)(W + 101619712);   // 15,728,640
    float*          offs   = (float*)(W + 121403392);            // 26,214,400
    float*          aw     = (float*)(W + 147617792);            // 13,107,200
    float*          out1   = (float*)(W + 160724992);            // 31,457,280

    dim3 bp(64, 4);

    // 1. flow composition
    k_flow<<<32, 256, 0, stream>>>(flow_f, flow_b, flows);
    // 2. big conv weight transforms
    t_wT<<<dim3(15,31), 256, 0, stream>>>(w_qk, wT_qk, 976, 31);
    t_wT<<<dim3(15,30), 256, 0, stream>>>(w_v,  wT_v,  960, 30);
    // 3. fused qk_in assembly (warp + pad + bf16)
    k_qkin<<<dim3(73,31,2), bp, 0, stream>>>(frame, flow_f, flow_b, flows, P_qk);
    // 4. frame -> padded tok bf16 (conv_v input)
    t_pad<<<dim3(73,30,2), bp, 0, stream>>>(frame, P_v, 960, 960, 0);
    // 5. conv_qk -> Q_tok (leaky)
    k_conv<1,0><<<dim3(15,16,2), 256, 0, stream>>>(P_qk, 992, 31, wT_qk, b_qk, nullptr,
                                                   nullptr, Q_tok, 960);
    // 6. conv_v -> V_tok (leaky)
    k_conv<1,0><<<dim3(15,16,2), 256, 0, stream>>>(P_v, 960, 30, wT_v, b_v, nullptr,
                                                   nullptr, V_tok, 960);
    // 7. small transforms (recycle wT_qk slot — safe after step 5)
    t_wT<<<dim3(3,6),  256, 0, stream>>>(w_ff, wT_ff, 192, 6);
    t_wT<<<dim3(3,12), 256, 0, stream>>>(w_f1, wT_f1, 384, 12);
    t_wT<<<dim3(3,6),  256, 0, stream>>>(w_f2, wT_f2, 192, 6);
    t_wg<<<3, 256, 0, stream>>>(w_vp,  nullptr, wg_vp, 192, 192);
    t_wg<<<4, 256, 0, stream>>>(w_off, w_at,    wg_oa, 160, 240);
    t_wg<<<3, 256, 0, stream>>>(w_out, nullptr, wg_out, 192, 192);
    // 8. zero borders of padded buffers built by epilogues
    t_zb<<<dim3(434,10), 256, 0, stream>>>(P_ff, 192);
    t_zb<<<dim3(434,10), 256, 0, stream>>>(P_mid, 192);
    // 9. v_proj GEMM -> vp bf16
    k_gemmm<0><<<dim3(3,16,10), 256, 0, stream>>>(V_tok, wg_vp, b_vp, nullptr,
                                                  nullptr, nullptr, vp);
    // 10. offsets + attn logits GEMM
    k_gemmm<1><<<dim3(4,16,10), 256, 0, stream>>>(Q_tok, wg_oa, b_off, b_at,
                                                  offs, aw, nullptr);
    // 11. softmax over 20
    k_softmax20<<<640, 256, 0, stream>>>(aw);
    // 12. deformable sampling -> acc_tok bf16
    k_sample<<<640, 256, 0, stream>>>(vp, offs, aw, flows, acc_tok);
    // 13. srcframe -> P_ffn1 cols 192..383 + all borders (after vp/V_tok dead)
    t_pad<<<dim3(73,6,10), bp, 0, stream>>>(srcframe, P_ffn1, 192, 384, 192);
    // 14. output projection -> P_ff (padded tok bf16 interior)
    k_gemmm<2><<<dim3(3,16,10), 256, 0, stream>>>(acc_tok, wg_out, b_out, nullptr,
                                                  nullptr, nullptr, P_ff);
    // 15. conv_ff + frame residual -> out1 fp32 AND P_ffn1 cols 0..191
    k_conv<1,1><<<dim3(3,16,10), 256, 0, stream>>>(P_ff, 192, 6, wT_ff, b_ff, frame,
                                                   out1, P_ffn1, 192);
    // 16. ffn1 (dilation 2, leaky) -> P_mid
    k_conv<2,2><<<dim3(3,16,10), 256, 0, stream>>>(P_ffn1, 384, 12, wT_f1, b_f1, nullptr,
                                                   nullptr, P_mid, 192);
    // 17. ffn2 + out1 residual -> d_out
    k_conv<1,3><<<dim3(3,16,10), 256, 0, stream>>>(P_mid, 192, 6, wT_f2, b_f2, out1,
                                                   out, nullptr, 192);
    // 18. second output = srcframe passthrough
    hipMemcpyAsync(out + (size_t)2*5*192*HWPX, srcframe,
                   (size_t)2*5*192*HWPX*sizeof(float),
                   hipMemcpyDeviceToDevice, stream);
}